// Round 5
// baseline (415.877 us; speedup 1.0000x reference)
//
#include <hip/hip_runtime.h>
#include <math.h>
#include <stdint.h>

#define L_DIM 1024
#define C_DIM 128
#define H_DIM 512
#define B_DIM 16
#define LC (L_DIM * C_DIM)      // 131072
#define BLC (B_DIM * LC)        // 2097152

typedef __attribute__((ext_vector_type(8))) short short8;
typedef __attribute__((ext_vector_type(4))) float floatx4;

// ---------------- monotone float/bits -> ordered uint ----------------------
__device__ __forceinline__ unsigned fordbits(unsigned u) {
    return (u & 0x80000000u) ? ~u : (u | 0x80000000u);
}

// ---------------- truncation 3-way bf16 split: x = h + m + l + O(2^-24 x) --
__device__ __forceinline__ void split3(float x, unsigned& uh, unsigned& um,
                                       unsigned& ul) {
    uh = __float_as_uint(x);
    const float r1 = x - __uint_as_float(uh & 0xffff0000u);
    um = __float_as_uint(r1);
    const float r2 = r1 - __uint_as_float(um & 0xffff0000u);
    ul = __float_as_uint(r2);
}

__device__ __forceinline__ float gelu_fast(float x) {
    const float g = 0.7978845608028654f * (x + 0.044715f * x * x * x);
    const float e = __expf(2.0f * g);
    const float t = 1.0f - 2.0f / (e + 1.0f);
    return 0.5f * x * (1.0f + t);
}

// ---------------- W pre-split into MFMA B-frag layout (h/m/l bf16) ---------
// Also zeroes the accum|gprefix|ghist block (16396 u32) every launch/replay.
__global__ __launch_bounds__(256) void wsplit_kernel(
    const float* __restrict__ W1, const float* __restrict__ W2,
    unsigned short* __restrict__ W1h, unsigned short* __restrict__ W1m,
    unsigned short* __restrict__ W1l, unsigned short* __restrict__ W2h,
    unsigned short* __restrict__ W2m, unsigned short* __restrict__ W2l,
    unsigned* __restrict__ zeroblk) {
    const int t = blockIdx.x * 256 + threadIdx.x;  // < 131072
    if (t < 16396) zeroblk[t] = 0u;
    unsigned uh, um, ul;
    if (t < 65536) {
        const int j = t & 7, lane = (t >> 3) & 63, nt = (t >> 9) & 31,
                  kt = (t >> 14) & 3;
        const int k = kt * 32 + (lane >> 4) * 8 + j;
        const int n = nt * 16 + (lane & 15);
        split3(W1[k * 512 + n], uh, um, ul);
        W1h[t] = (unsigned short)(uh >> 16);
        W1m[t] = (unsigned short)(um >> 16);
        W1l[t] = (unsigned short)(ul >> 16);
    } else {
        const int t2 = t - 65536;
        const int j = t2 & 7, lane = (t2 >> 3) & 63, nt = (t2 >> 9) & 7,
                  kt = (t2 >> 12) & 15;
        const int k = kt * 32 + (lane >> 4) * 8 + j;
        const int n = nt * 16 + (lane & 15);
        split3(W2[k * 128 + n], uh, um, ul);
        W2h[t2] = (unsigned short)(uh >> 16);
        W2m[t2] = (unsigned short)(um >> 16);
        W2l[t2] = (unsigned short)(ul >> 16);
    }
}

// 6-term bf16x3 MFMA accumulate (small terms first); error ~2^-24
#define MFMA6(AH, AM, AL, BH, BM, BL, ACC)                                    \
    ACC = __builtin_amdgcn_mfma_f32_16x16x32_bf16(AL, BH, ACC, 0, 0, 0);      \
    ACC = __builtin_amdgcn_mfma_f32_16x16x32_bf16(AM, BM, ACC, 0, 0, 0);      \
    ACC = __builtin_amdgcn_mfma_f32_16x16x32_bf16(AH, BL, ACC, 0, 0, 0);      \
    ACC = __builtin_amdgcn_mfma_f32_16x16x32_bf16(AM, BH, ACC, 0, 0, 0);      \
    ACC = __builtin_amdgcn_mfma_f32_16x16x32_bf16(AH, BM, ACC, 0, 0, 0);      \
    ACC = __builtin_amdgcn_mfma_f32_16x16x32_bf16(AH, BH, ACC, 0, 0, 0);

// XOR-swizzled LDS address for A-tiles: 32 rows x 128 cols of ushort,
// addr = row*128 + ((chunk ^ (row&15))<<3) + (col&7), chunk = col>>3.
__device__ __forceinline__ int swz(int row, int col) {
    return row * 128 + ((((col >> 3) ^ (row & 15))) << 3) + (col & 7);
}

// ---------------- fused MLP (+ previous step's DPM update when UPD) --------
// R5: 1024-thr blocks (16 waves), 512 blocks -> 32 waves/CU (was 16).
// Work split: GEMM1 nt = q2*16 + w (w 0..15); GEMM2 wave owns
// (il = w>>3, ncol-tile = w&7). Same W traffic, same MFMA totals, same LDS;
// 2x the waves to hide W-fragment L2 latency (R4 PMC: all pipes <25%,
// occupancy 30% -> latency-bound). A-frags reloaded per q2 to stay <=64 VGPR
// (required for 8 waves/EU).
template <int UPD>
__global__ __launch_bounds__(1024, 8) void mlp_kernel(
    float* __restrict__ z, const float* __restrict__ zr,
    const float* __restrict__ y, const float* __restrict__ mk,
    const unsigned short* __restrict__ W1h, const unsigned short* __restrict__ W1m,
    const unsigned short* __restrict__ W1l, const unsigned short* __restrict__ W2h,
    const unsigned short* __restrict__ W2m, const unsigned short* __restrict__ W2l,
    const float* __restrict__ b1, const float* __restrict__ tw,
    const float* __restrict__ b2, float t_feat,
    float* __restrict__ eps_buf, float* __restrict__ ent,
    const float* __restrict__ cA, const float* __restrict__ cB,
    const float* __restrict__ cG, float* __restrict__ accum) {
    __shared__ unsigned short lds2[2][3][4096];  // [0]=zA staging, rotation
    __shared__ float red1[16], red2[16];
    const int tid = threadIdx.x;
    const int w = tid >> 6, lane = tid & 63;
    const int quad = lane >> 4, m16 = lane & 15;
    const int il_w = w >> 3, w8 = w & 7;
    const int l0 = blockIdx.x * 2;

    // ---- phase 1: (coeff-map update) + stats + stage split z into LDS ----
    float s1 = 0.f, s2 = 0.f;
    {
        const int f = tid * 4;  // 0..4092
        const int r_ = f >> 7, cb = f & 127;
        const int b = r_ & 15, il = r_ >> 4, l = l0 + il;
        const size_t g = ((size_t)b * 1024 + l) * 128 + cb;
        float4 zv = *(const float4*)(zr + g);
        const float4 yv = *(const float4*)(y + g);
        const float4 mv = *(const float4*)(mk + g);
        if (UPD) {
            const float4 ev = *(const float4*)(eps_buf + g);
            const int pix = l * 128 + cb;
            const float4 a4 = *(const float4*)(cA + pix);
            const float4 b4 = *(const float4*)(cB + pix);
            const float4 g4 = *(const float4*)(cG + pix);
            zv.x = a4.x * zv.x - b4.x * ev.x - g4.x * ((zv.x - yv.x) * mv.x);
            zv.y = a4.y * zv.y - b4.y * ev.y - g4.y * ((zv.y - yv.y) * mv.y);
            zv.z = a4.z * zv.z - b4.z * ev.z - g4.z * ((zv.z - yv.z) * mv.z);
            zv.w = a4.w * zv.w - b4.w * ev.w - g4.w * ((zv.w - yv.w) * mv.w);
            *(float4*)(z + g) = zv;
        }
        float oe;
        oe = (zv.x - yv.x) * mv.x; s1 += oe; s2 += oe * oe;
        oe = (zv.y - yv.y) * mv.y; s1 += oe; s2 += oe * oe;
        oe = (zv.z - yv.z) * mv.z; s1 += oe; s2 += oe * oe;
        oe = (zv.w - yv.w) * mv.w; s1 += oe; s2 += oe * oe;

        // swizzled staging (ushort4 = 8B per array; conflict-free)
        const int base = swz(r_, cb);
        const float xs[4] = {zv.x, zv.y, zv.z, zv.w};
        ushort4 vh, vm, vl;
        unsigned uh, um, ul;
        split3(xs[0], uh, um, ul); vh.x = uh >> 16; vm.x = um >> 16; vl.x = ul >> 16;
        split3(xs[1], uh, um, ul); vh.y = uh >> 16; vm.y = um >> 16; vl.y = ul >> 16;
        split3(xs[2], uh, um, ul); vh.z = uh >> 16; vm.z = um >> 16; vl.z = ul >> 16;
        split3(xs[3], uh, um, ul); vh.w = uh >> 16; vm.w = um >> 16; vl.w = ul >> 16;
        *(ushort4*)(&lds2[0][0][base]) = vh;
        *(ushort4*)(&lds2[0][1][base]) = vm;
        *(ushort4*)(&lds2[0][2][base]) = vl;
    }
#pragma unroll
    for (int off = 32; off; off >>= 1) {
        s1 += __shfl_down(s1, off);
        s2 += __shfl_down(s2, off);
    }
    if (lane == 0) { red1[w] = s1; red2[w] = s2; }
    __syncthreads();  // staging + red complete
    if (tid == 0) {
        float a1 = 0.f, a2 = 0.f;
#pragma unroll
        for (int i = 0; i < 16; ++i) { a1 += red1[i]; a2 += red2[i]; }
        atomicAdd(&accum[0], a1);
        atomicAdd(&accum[1], a2);
    }

    // ---- GEMM1: wave's nt = q2*16 + w; acc1[q2*2+il] ----
    floatx4 acc1[4];
#pragma unroll
    for (int i = 0; i < 4; ++i) acc1[i] = (floatx4){0.f, 0.f, 0.f, 0.f};

#pragma unroll
    for (int kt = 0; kt < 4; ++kt) {
#pragma unroll
        for (int q2 = 0; q2 < 2; ++q2) {
            const size_t off = ((size_t)(kt * 32 + q2 * 16 + w) * 64 + lane) * 8;
            const short8 bh = *(const short8*)(W1h + off);
            const short8 bm = *(const short8*)(W1m + off);
            const short8 bl = *(const short8*)(W1l + off);
#pragma unroll
            for (int il = 0; il < 2; ++il) {
                const int fb = swz(il * 16 + m16, kt * 32 + quad * 8);
                const short8 Ah = *(const short8*)(&lds2[0][0][fb]);
                const short8 Am = *(const short8*)(&lds2[0][1][fb]);
                const short8 Al = *(const short8*)(&lds2[0][2][fb]);
                floatx4 a = acc1[q2 * 2 + il];
                MFMA6(Ah, Am, Al, bh, bm, bl, a);
                acc1[q2 * 2 + il] = a;
            }
        }
    }

    // ---- quarter phases: owning 8 waves write h, all 16 run GEMM2 ----
    floatx4 acc2 = (floatx4){0.f, 0.f, 0.f, 0.f};

#pragma unroll
    for (int q = 0; q < 4; ++q) {
        const int bi = (q & 1) ^ 1;  // q even -> buf1, q odd -> buf0 (zA dead)
        if (il_w == (q & 1)) {  // owning waves hold nt = (q>>1)*16 + w
            const int colg = q * 128 + w8 * 16 + m16;
            const float bb = b1[colg] + t_feat * tw[colg];
            const int kcol = w8 * 16 + m16;  // quarter-local k col
#pragma unroll
            for (int il = 0; il < 2; ++il) {
#pragma unroll
                for (int r = 0; r < 4; ++r) {
                    const float x = gelu_fast(acc1[(q >> 1) * 2 + il][r] + bb);
                    unsigned uh, um, ul;
                    split3(x, uh, um, ul);
                    const int idx = swz(il * 16 + quad * 4 + r, kcol);
                    lds2[bi][0][idx] = (unsigned short)(uh >> 16);
                    lds2[bi][1][idx] = (unsigned short)(um >> 16);
                    lds2[bi][2][idx] = (unsigned short)(ul >> 16);
                }
            }
        }
        __syncthreads();  // write(buf bi) visible; buffers alternate => safe

#pragma unroll
        for (int ktl = 0; ktl < 4; ++ktl) {
            const int fb = swz(il_w * 16 + m16, ktl * 32 + quad * 8);
            const short8 Ah2 = *(const short8*)(&lds2[bi][0][fb]);
            const short8 Am2 = *(const short8*)(&lds2[bi][1][fb]);
            const short8 Al2 = *(const short8*)(&lds2[bi][2][fb]);
            const size_t off =
                ((size_t)((q * 4 + ktl) * 8 + w8) * 64 + lane) * 8;
            const short8 bh = *(const short8*)(W2h + off);
            const short8 bm = *(const short8*)(W2m + off);
            const short8 bl = *(const short8*)(W2l + off);
            MFMA6(Ah2, Am2, Al2, bh, bm, bl, acc2);
        }
    }

    // ---- epilogue: +b2, write eps, ent = mean_b |eps| ----
    {
        const int col = w8 * 16 + m16;
        const float bb2 = b2[col];
        float pa = 0.f;
#pragma unroll
        for (int r = 0; r < 4; ++r) {
            const float e = acc2[r] + bb2;
            const int b = quad * 4 + r;
            eps_buf[((size_t)b * 1024 + l0 + il_w) * 128 + col] = e;
            pa += fabsf(e);
        }
        pa += __shfl_xor(pa, 16);
        pa += __shfl_xor(pa, 32);
        if (quad == 0) ent[(l0 + il_w) * 128 + col] = pa * (1.0f / 16.0f);
    }
}

// ======================= select path, barrier-free =========================
// Kernel boundaries are the global barriers; all cross-kernel reads are
// plain loads.

// ---- S1: pools (proven summation order) + 14-bit fordbits hist (scale 0) --
__global__ __launch_bounds__(256) void pools_kernel(
    const float* __restrict__ ent, float* __restrict__ p1,
    float* __restrict__ p2, float* __restrict__ p3,
    unsigned* __restrict__ ghist) {
    __shared__ unsigned lh[8192];
    const int tid = threadIdx.x;
    const int gid = blockIdx.x * 256 + tid;  // < 65536
    for (int i = tid; i < 8192; i += 256) lh[i] = 0u;
    __syncthreads();

    // ent histogram (scale 0): 2 elements/thread into packed block hist
    {
        const float2 ev = *(const float2*)(ent + (size_t)gid * 2);
        const unsigned b0 = fordbits(__float_as_uint(ev.x)) >> 18;
        const unsigned b1_ = fordbits(__float_as_uint(ev.y)) >> 18;
        atomicAdd(&lh[b0 >> 1], 1u << ((b0 & 1) << 4));
        atomicAdd(&lh[b1_ >> 1], 1u << ((b1_ & 1) << 4));
    }
    // p1: w=2, 512x64
    if (gid < 32768) {
        const int r = gid >> 6, c = gid & 63;
        float s = 0.f;
#pragma unroll
        for (int ii = 0; ii < 2; ++ii) {
            const float2 e = *(const float2*)(ent + (((r * 2 + ii) << 7) + c * 2));
            s += e.x; s += e.y;
        }
        p1[gid] = s * 0.25f;
    }
    // p2: w=4, 256x32
    if (gid < 8192) {
        const int r = gid >> 5, c = gid & 31;
        float s = 0.f;
#pragma unroll
        for (int ii = 0; ii < 4; ++ii) {
            const float4 e = *(const float4*)(ent + (((r * 4 + ii) << 7) + c * 4));
            s += e.x; s += e.y; s += e.z; s += e.w;
        }
        p2[gid] = s * 0.0625f;
    }
    // p3: w=8, 128x16
    if (gid < 2048) {
        const int r = gid >> 4, c = gid & 15;
        float s = 0.f;
#pragma unroll
        for (int ii = 0; ii < 8; ++ii) {
            const float4 ea = *(const float4*)(ent + (((r * 8 + ii) << 7) + c * 8));
            const float4 eb = *(const float4*)(ent + (((r * 8 + ii) << 7) + c * 8 + 4));
            s += ea.x; s += ea.y; s += ea.z; s += ea.w;
            s += eb.x; s += eb.y; s += eb.z; s += eb.w;
        }
        p3[gid] = s * (1.0f / 64.0f);
    }
    __syncthreads();
    // merge packed nonzero bins to global
    for (int i = tid; i < 8192; i += 256) {
        const unsigned v = lh[i];
        if (v & 0xFFFFu) atomicAdd(&ghist[2 * i], v & 0xFFFFu);
        if (v >> 16) atomicAdd(&ghist[2 * i + 1], v >> 16);
    }
}

#define CAND_CAP 16384

// ---- register-resident exact Kth-largest for small pools (scales 1..3) ----
template <int NPT4, int N, unsigned K>
__device__ __forceinline__ void small_select(
    const float* __restrict__ data, unsigned* __restrict__ gout, const int t,
    const int w8, unsigned* __restrict__ histcand,
    unsigned* __restrict__ part, unsigned (*hrep)[512],
    unsigned* sh_b, unsigned* sh_krem, unsigned* sh_cnt, unsigned* sh_d,
    unsigned* sh_k2) {
    // batched vector load into registers (phantom -1e30 < all real values)
    float4 xv[NPT4];
#pragma unroll
    for (int i = 0; i < NPT4; ++i) {
        const int idx4 = t + i * 1024;
        if (idx4 < (N >> 2)) xv[i] = ((const float4*)data)[idx4];
        else xv[i] = (float4){-1e30f, -1e30f, -1e30f, -1e30f};
    }
    unsigned u[NPT4 * 4];
#pragma unroll
    for (int i = 0; i < NPT4; ++i) {
        u[4 * i + 0] = fordbits(__float_as_uint(xv[i].x));
        u[4 * i + 1] = fordbits(__float_as_uint(xv[i].y));
        u[4 * i + 2] = fordbits(__float_as_uint(xv[i].z));
        u[4 * i + 3] = fordbits(__float_as_uint(xv[i].w));
    }
    if (t == 0) { *sh_b = 0u; *sh_krem = 1u; *sh_cnt = 0u; *sh_d = 0u; *sh_k2 = 1u; }
    for (int i = t; i < 16384; i += 1024) histcand[i] = 0u;
    __syncthreads();
#pragma unroll
    for (int j = 0; j < NPT4 * 4; ++j) atomicAdd(&histcand[u[j] >> 18], 1u);
    __syncthreads();
    // suffix scan over 16384 bins: 16/thread, then 1024-block scan
    {
        unsigned s = 0;
#pragma unroll
        for (int j = 0; j < 16; ++j) s += histcand[t * 16 + j];
        part[t] = s;
    }
    __syncthreads();
    for (int off = 1; off < 1024; off <<= 1) {
        const unsigned v = (t + off < 1024) ? part[t + off] : 0u;
        __syncthreads();
        part[t] += v;
        __syncthreads();
    }
    {
        const unsigned suf = part[t];
        const unsigned sufn = (t < 1023) ? part[t + 1] : 0u;
        if (suf >= K && sufn < K) {
            unsigned run = sufn;
            for (int b = 15; b >= 0; --b) {
                const unsigned hb = histcand[t * 16 + b];
                run += hb;
                if (run >= K) {
                    *sh_b = (unsigned)(t * 16 + b);
                    *sh_krem = K - (run - hb);
                    break;
                }
            }
        }
    }
    __syncthreads();
    const unsigned b14 = *sh_b;
    unsigned krem = *sh_krem;
    __syncthreads();  // all histcand reads done before cand overwrite
    // compact candidates from registers into histcand-as-cand
#pragma unroll
    for (int j = 0; j < NPT4 * 4; ++j)
        if ((u[j] >> 18) == b14) {
            const unsigned p = atomicAdd(sh_cnt, 1u);
            if (p < CAND_CAP) histcand[p] = u[j];
        }
    __syncthreads();
    const unsigned cnt = *sh_cnt;
    const bool inlds = (cnt <= CAND_CAP);
    // ---- refine bits 17..9 ----
    for (int i = t; i < 4096; i += 1024) ((unsigned*)hrep)[i] = 0u;
    __syncthreads();
    if (inlds) {
        for (unsigned i = t; i < cnt; i += 1024)
            atomicAdd(&hrep[w8][(histcand[i] >> 9) & 511u], 1u);
    } else {
#pragma unroll
        for (int j = 0; j < NPT4 * 4; ++j)
            if ((u[j] >> 18) == b14)
                atomicAdd(&hrep[w8][(u[j] >> 9) & 511u], 1u);
    }
    __syncthreads();
    if (t < 512) {
        unsigned s = 0;
#pragma unroll
        for (int r = 0; r < 8; ++r) s += hrep[r][t];
        part[t] = s;
    }
    __syncthreads();
    for (int off = 1; off < 512; off <<= 1) {
        unsigned v = 0u;
        if (t < 512) v = (t + off < 512) ? part[t + off] : 0u;
        __syncthreads();
        if (t < 512) part[t] += v;
        __syncthreads();
    }
    if (t < 512) {
        const unsigned suf = part[t];
        const unsigned sufn = (t < 511) ? part[t + 1] : 0u;
        if (suf >= krem && sufn < krem) { *sh_d = (unsigned)t; *sh_k2 = krem - sufn; }
    }
    __syncthreads();
    const unsigned dA = *sh_d;
    krem = *sh_k2;
    __syncthreads();
    // ---- refine bits 8..0 ----
    for (int i = t; i < 4096; i += 1024) ((unsigned*)hrep)[i] = 0u;
    __syncthreads();
    if (inlds) {
        for (unsigned i = t; i < cnt; i += 1024) {
            const unsigned c = histcand[i];
            if (((c >> 9) & 511u) == dA) atomicAdd(&hrep[w8][c & 511u], 1u);
        }
    } else {
#pragma unroll
        for (int j = 0; j < NPT4 * 4; ++j)
            if ((u[j] >> 18) == b14 && ((u[j] >> 9) & 511u) == dA)
                atomicAdd(&hrep[w8][u[j] & 511u], 1u);
    }
    __syncthreads();
    if (t < 512) {
        unsigned s = 0;
#pragma unroll
        for (int r = 0; r < 8; ++r) s += hrep[r][t];
        part[t] = s;
    }
    __syncthreads();
    for (int off = 1; off < 512; off <<= 1) {
        unsigned v = 0u;
        if (t < 512) v = (t + off < 512) ? part[t + off] : 0u;
        __syncthreads();
        if (t < 512) part[t] += v;
        __syncthreads();
    }
    if (t < 512) {
        const unsigned suf = part[t];
        const unsigned sufn = (t < 511) ? part[t + 1] : 0u;
        if (suf >= krem && sufn < krem)
            gout[0] = (b14 << 18) | (dA << 9) | (unsigned)t;
    }
}

// ---- S2: exact K-th-largest thresholds. 4 blocks x 1024 thr (1/scale). ----
__global__ __launch_bounds__(1024, 1) void thresh_kernel(
    const float* __restrict__ ent, const float* __restrict__ p1,
    const float* __restrict__ p2, const float* __restrict__ p3,
    const unsigned* __restrict__ ghist, unsigned* __restrict__ gprefix) {
    const int scale = blockIdx.x, t = threadIdx.x;
    __shared__ unsigned histcand[16384];  // 14-bit hist, then candidates
    __shared__ unsigned part[1024];
    __shared__ unsigned hrep[8][512];
    __shared__ unsigned sh_b, sh_krem, sh_cnt, sh_d, sh_k2;
    const int w8 = (t >> 6) & 7;

    if (scale == 1) {
        small_select<8, 32768, 6553u>(p1, &gprefix[1], t, w8, histcand, part,
                                      hrep, &sh_b, &sh_krem, &sh_cnt, &sh_d,
                                      &sh_k2);
        return;
    }
    if (scale == 2) {
        small_select<2, 8192, 1638u>(p2, &gprefix[2], t, w8, histcand, part,
                                     hrep, &sh_b, &sh_krem, &sh_cnt, &sh_d,
                                     &sh_k2);
        return;
    }
    if (scale == 3) {
        small_select<1, 2048, 409u>(p3, &gprefix[3], t, w8, histcand, part,
                                    hrep, &sh_b, &sh_krem, &sh_cnt, &sh_d,
                                    &sh_k2);
        return;
    }

    // ---------------- scale 0: ent, N=131072, K=26214 ----------------
    const unsigned K = 26214u;
    if (t == 0) { sh_b = 0u; sh_krem = 1u; sh_cnt = 0u; sh_d = 0u; sh_k2 = 1u; }

    // 14-bit bucket from global hist: 16 bins/thread + block suffix scan
    {
        unsigned s = 0;
        const uint4* h4 = (const uint4*)(ghist + t * 16);
#pragma unroll
        for (int j = 0; j < 4; ++j) {
            const uint4 x = h4[j];
            s += x.x + x.y + x.z + x.w;
        }
        part[t] = s;
    }
    __syncthreads();
    for (int off = 1; off < 1024; off <<= 1) {
        const unsigned v = (t + off < 1024) ? part[t + off] : 0u;
        __syncthreads();
        part[t] += v;
        __syncthreads();
    }
    {
        const unsigned suf = part[t];
        const unsigned sufn = (t < 1023) ? part[t + 1] : 0u;
        if (suf >= K && sufn < K) {  // unique crossing chunk
            unsigned run = sufn;
            for (int b = 15; b >= 0; --b) {
                const unsigned hb = ghist[t * 16 + b];
                run += hb;
                if (run >= K) {
                    sh_b = (unsigned)(t * 16 + b);
                    sh_krem = K - (run - hb);
                    break;
                }
            }
        }
    }
    __syncthreads();
    const unsigned b14 = sh_b;
    unsigned krem = sh_krem;

    // compact in-bucket candidates into LDS; batched 8x float4 loads
    for (int base = 0; base < 32768; base += 8192) {
        float4 w4[8];
#pragma unroll
        for (int i = 0; i < 8; ++i)
            w4[i] = ((const float4*)ent)[base + i * 1024 + t];
#pragma unroll
        for (int i = 0; i < 8; ++i) {
            const float xs[4] = {w4[i].x, w4[i].y, w4[i].z, w4[i].w};
#pragma unroll
            for (int j = 0; j < 4; ++j) {
                const unsigned uu = fordbits(__float_as_uint(xs[j]));
                if ((uu >> 18) == b14) {
                    const unsigned p = atomicAdd(&sh_cnt, 1u);
                    if (p < CAND_CAP) histcand[p] = uu;
                }
            }
        }
    }
    __syncthreads();
    const unsigned cnt = sh_cnt;
    const bool inlds = (cnt <= CAND_CAP);

    // ---- refine bits 17..9 ----
    for (int i = t; i < 4096; i += 1024) ((unsigned*)hrep)[i] = 0u;
    __syncthreads();
    if (inlds) {
        for (unsigned i = t; i < cnt; i += 1024)
            atomicAdd(&hrep[w8][(histcand[i] >> 9) & 511u], 1u);
    } else {
        for (int base = 0; base < 32768; base += 8192) {
            float4 w4[8];
#pragma unroll
            for (int i = 0; i < 8; ++i)
                w4[i] = ((const float4*)ent)[base + i * 1024 + t];
#pragma unroll
            for (int i = 0; i < 8; ++i) {
                const float xs[4] = {w4[i].x, w4[i].y, w4[i].z, w4[i].w};
#pragma unroll
                for (int j = 0; j < 4; ++j) {
                    const unsigned uu = fordbits(__float_as_uint(xs[j]));
                    if ((uu >> 18) == b14)
                        atomicAdd(&hrep[w8][(uu >> 9) & 511u], 1u);
                }
            }
        }
    }
    __syncthreads();
    if (t < 512) {
        unsigned s = 0;
#pragma unroll
        for (int r = 0; r < 8; ++r) s += hrep[r][t];
        part[t] = s;
    }
    __syncthreads();
    for (int off = 1; off < 512; off <<= 1) {
        unsigned v = 0u;
        if (t < 512) v = (t + off < 512) ? part[t + off] : 0u;
        __syncthreads();
        if (t < 512) part[t] += v;
        __syncthreads();
    }
    if (t < 512) {
        const unsigned suf = part[t];
        const unsigned sufn = (t < 511) ? part[t + 1] : 0u;
        if (suf >= krem && sufn < krem) { sh_d = (unsigned)t; sh_k2 = krem - sufn; }
    }
    __syncthreads();
    const unsigned dA = sh_d;
    krem = sh_k2;
    __syncthreads();

    // ---- refine bits 8..0 ----
    for (int i = t; i < 4096; i += 1024) ((unsigned*)hrep)[i] = 0u;
    __syncthreads();
    if (inlds) {
        for (unsigned i = t; i < cnt; i += 1024) {
            const unsigned c = histcand[i];
            if (((c >> 9) & 511u) == dA) atomicAdd(&hrep[w8][c & 511u], 1u);
        }
    } else {
        for (int base = 0; base < 32768; base += 8192) {
            float4 w4[8];
#pragma unroll
            for (int i = 0; i < 8; ++i)
                w4[i] = ((const float4*)ent)[base + i * 1024 + t];
#pragma unroll
            for (int i = 0; i < 8; ++i) {
                const float xs[4] = {w4[i].x, w4[i].y, w4[i].z, w4[i].w};
#pragma unroll
                for (int j = 0; j < 4; ++j) {
                    const unsigned uu = fordbits(__float_as_uint(xs[j]));
                    if ((uu >> 18) == b14 && ((uu >> 9) & 511u) == dA)
                        atomicAdd(&hrep[w8][uu & 511u], 1u);
                }
            }
        }
    }
    __syncthreads();
    if (t < 512) {
        unsigned s = 0;
#pragma unroll
        for (int r = 0; r < 8; ++r) s += hrep[r][t];
        part[t] = s;
    }
    __syncthreads();
    for (int off = 1; off < 512; off <<= 1) {
        unsigned v = 0u;
        if (t < 512) v = (t + off < 512) ? part[t + off] : 0u;
        __syncthreads();
        if (t < 512) part[t] += v;
        __syncthreads();
    }
    if (t < 512) {
        const unsigned suf = part[t];
        const unsigned sufn = (t < 511) ? part[t + 1] : 0u;
        if (suf >= krem && sufn < krem)
            gprefix[0] = (b14 << 18) | (dA << 9) | (unsigned)t;
    }
}

// ---- S3: per-pixel coeff maps, plain streaming loads; zeroes hist next ----
__global__ __launch_bounds__(256) void coeff_kernel(
    const float* __restrict__ ent, const float* __restrict__ p1,
    const float* __restrict__ p2, const float* __restrict__ p3,
    const unsigned* __restrict__ gprefix, const float* __restrict__ accum_si,
    float* __restrict__ cA, float* __restrict__ cB, float* __restrict__ cG,
    unsigned* __restrict__ ghist, float base_a, float base_b, float h_lam) {
    const int i = blockIdx.x * 256 + threadIdx.x;  // < 131072
    // zero 14-bit histogram for the next step's pools_kernel
    if (i < 16384) ghist[i] = 0u;

    const unsigned t0 = gprefix[0], t1 = gprefix[1], t2 = gprefix[2],
                   t3 = gprefix[3];
    const float mean = accum_si[0] * (1.0f / (float)BLC);
    const float var = accum_si[1] * (1.0f / (float)BLC) - mean * mean;
    const float vinv = 1.0f / (var + 1e-8f);

    const int l = i >> 7, c = i & 127;
    float ent_v = 0.f;
    bool sel = false;
    const float v0 = ent[i];
    if (fordbits(__float_as_uint(v0)) >= t0) { ent_v = v0; sel = true; }
    else {
        const float v1 = p1[((l >> 1) << 6) + (c >> 1)];
        if (fordbits(__float_as_uint(v1)) >= t1) { ent_v = v1; sel = true; }
        else {
            const float v2 = p2[((l >> 2) << 5) + (c >> 2)];
            if (fordbits(__float_as_uint(v2)) >= t2) { ent_v = v2; sel = true; }
            else {
                const float v3 = p3[((l >> 3) << 4) + (c >> 3)];
                if (fordbits(__float_as_uint(v3)) >= t3) { ent_v = v3; sel = true; }
            }
        }
    }
    if (sel) {
        float corr;
        if (ent_v > 0.5f)
            corr = 1.0f + h_lam + h_lam * h_lam * (1.0f / 3.0f);
        else if (ent_v > 0.1f)
            corr = 1.0f + 0.5f * h_lam;
        else
            corr = 1.0f;
        cA[i] = base_a;
        cB[i] = base_b * corr;
        cG[i] = (2.0f * ent_v / (ent_v + 1.0f)) * vinv;
    } else {
        cA[i] = 1.0f;
        cB[i] = 0.f;
        cG[i] = 0.f;
    }
}

// ---------------- standalone final update (coeff-map streaming) ------------
__global__ __launch_bounds__(256) void update_kernel(
    float* __restrict__ z, const float* __restrict__ y,
    const float* __restrict__ mk, const float* __restrict__ eps,
    const float* __restrict__ cA, const float* __restrict__ cB,
    const float* __restrict__ cG) {
    const int idx = blockIdx.x * 256 + threadIdx.x;  // < BLC
    const int p = idx & (LC - 1);
    const float zi = z[idx];
    z[idx] = cA[p] * zi - cB[p] * eps[idx] - cG[p] * ((zi - y[idx]) * mk[idx]);
}

// ---------------------------------------------------------------------------
extern "C" void kernel_launch(void* const* d_in, const int* in_sizes, int n_in,
                              void* d_out, int out_size, void* d_ws,
                              size_t ws_size, hipStream_t stream) {
    const float* y_obs = (const float*)d_in[0];
    const float* mask = (const float*)d_in[1];
    const float* z_init = (const float*)d_in[2];
    const float* W1 = (const float*)d_in[3];
    const float* b1 = (const float*)d_in[4];
    const float* W2 = (const float*)d_in[5];
    const float* b2 = (const float*)d_in[6];
    const float* tw = (const float*)d_in[7];
    float* z = (float*)d_out;
    float* ws = (float*)d_ws;

    // workspace layout (float offsets); end = 2877452 floats = 11,509,808 B
    float* eps = ws;                                 // 2097152
    float* ent = ws + 2097152;                       // 131072
    float* p1 = ws + 2228224;                        // 32768
    float* p2 = ws + 2260992;                        // 8192
    float* p3 = ws + 2269184;                        // 2048
    float* cA = ws + 2271232;                        // 131072
    float* cB = ws + 2402304;                        // 131072
    float* cG = ws + 2533376;                        // 131072
    // zero block: accum[8] | gprefix[4] | ghist[16384] (contig 16396 u32)
    float* accum = ws + 2664448;                     // 8 (2 per step)
    unsigned* gprefix = (unsigned*)(ws + 2664456);   // 4
    unsigned* ghist = (unsigned*)(ws + 2664460);     // 16384 u32
    unsigned short* W1h = (unsigned short*)(ws + 2680844);  // 65536 u16 each
    unsigned short* W1m = (unsigned short*)(ws + 2713612);
    unsigned short* W1l = (unsigned short*)(ws + 2746380);
    unsigned short* W2h = (unsigned short*)(ws + 2779148);
    unsigned short* W2m = (unsigned short*)(ws + 2811916);
    unsigned short* W2l = (unsigned short*)(ws + 2844684);

    // diffusion schedule in fp32 (input-independent)
    float alpha_[1000], sigma_[1000], lam_[1000];
    {
        float ac = 1.0f;
        for (int i = 0; i < 1000; ++i) {
            const float beta = 1e-4f + (0.02f - 1e-4f) * ((float)i / 999.0f);
            ac = ac * (1.0f - beta);
            alpha_[i] = sqrtf(ac);
            sigma_[i] = sqrtf(1.0f - ac);
            lam_[i] = logf(alpha_[i]) - logf(sigma_[i]);
        }
    }
    float tf[4], hl[4], ba[4], bb[4];
    for (int si = 0; si < 4; ++si) {
        const int k = 999 - si * 250;
        const int kp = (k - 250 > 0) ? (k - 250) : 0;
        tf[si] = (float)k / 1000.0f;
        hl[si] = lam_[kp] - lam_[k];
        ba[si] = alpha_[kp] / alpha_[k];
        bb[si] = sigma_[kp] * (expf(hl[si]) - 1.0f);
    }

    // wsplit also zeroes accum|gprefix|ghist every launch/replay
    wsplit_kernel<<<512, 256, 0, stream>>>(W1, W2, W1h, W1m, W1l, W2h, W2m,
                                           W2l, (unsigned*)accum);

    for (int si = 0; si < 4; ++si) {
        // z is first WRITTEN at si=1; si=0,1 read z_init directly (no memcpy)
        const float* zrd = (si <= 1) ? z_init : z;
        if (si == 0) {
            mlp_kernel<0><<<512, 1024, 0, stream>>>(
                z, zrd, y_obs, mask, W1h, W1m, W1l, W2h, W2m, W2l, b1, tw, b2,
                tf[0], eps, ent, cA, cB, cG, accum);
        } else {
            mlp_kernel<1><<<512, 1024, 0, stream>>>(
                z, zrd, y_obs, mask, W1h, W1m, W1l, W2h, W2m, W2l, b1, tw, b2,
                tf[si], eps, ent, cA, cB, cG, accum + 2 * si);
        }
        pools_kernel<<<256, 256, 0, stream>>>(ent, p1, p2, p3, ghist);
        thresh_kernel<<<4, 1024, 0, stream>>>(ent, p1, p2, p3, ghist, gprefix);
        coeff_kernel<<<512, 256, 0, stream>>>(ent, p1, p2, p3, gprefix,
                                              accum + 2 * si, cA, cB, cG,
                                              ghist, ba[si], bb[si], hl[si]);
    }
    update_kernel<<<8192, 256, 0, stream>>>(z, y_obs, mask, eps, cA, cB, cG);
}

// Round 6
// 384.182 us; speedup vs baseline: 1.0825x; 1.0825x over previous
//
#include <hip/hip_runtime.h>
#include <math.h>
#include <stdint.h>

#define L_DIM 1024
#define C_DIM 128
#define H_DIM 512
#define B_DIM 16
#define LC (L_DIM * C_DIM)      // 131072
#define BLC (B_DIM * LC)        // 2097152

typedef __attribute__((ext_vector_type(8))) short short8;
typedef __attribute__((ext_vector_type(4))) float floatx4;

// ---------------- monotone float/bits -> ordered uint ----------------------
__device__ __forceinline__ unsigned fordbits(unsigned u) {
    return (u & 0x80000000u) ? ~u : (u | 0x80000000u);
}

// ---------------- truncation 3-way bf16 split: x = h + m + l + O(2^-24 x) --
__device__ __forceinline__ void split3(float x, unsigned& uh, unsigned& um,
                                       unsigned& ul) {
    uh = __float_as_uint(x);
    const float r1 = x - __uint_as_float(uh & 0xffff0000u);
    um = __float_as_uint(r1);
    const float r2 = r1 - __uint_as_float(um & 0xffff0000u);
    ul = __float_as_uint(r2);
}

__device__ __forceinline__ float gelu_fast(float x) {
    const float g = 0.7978845608028654f * (x + 0.044715f * x * x * x);
    const float e = __expf(2.0f * g);
    const float t = 1.0f - 2.0f / (e + 1.0f);
    return 0.5f * x * (1.0f + t);
}

// ---------------- W pre-split into MFMA B-frag layout (h/m/l bf16) ---------
// Also zeroes the accum|gprefix|ghist block (16396 u32) every launch/replay.
__global__ __launch_bounds__(256) void wsplit_kernel(
    const float* __restrict__ W1, const float* __restrict__ W2,
    unsigned short* __restrict__ W1h, unsigned short* __restrict__ W1m,
    unsigned short* __restrict__ W1l, unsigned short* __restrict__ W2h,
    unsigned short* __restrict__ W2m, unsigned short* __restrict__ W2l,
    unsigned* __restrict__ zeroblk) {
    const int t = blockIdx.x * 256 + threadIdx.x;  // < 131072
    if (t < 16396) zeroblk[t] = 0u;
    unsigned uh, um, ul;
    if (t < 65536) {
        const int j = t & 7, lane = (t >> 3) & 63, nt = (t >> 9) & 31,
                  kt = (t >> 14) & 3;
        const int k = kt * 32 + (lane >> 4) * 8 + j;
        const int n = nt * 16 + (lane & 15);
        split3(W1[k * 512 + n], uh, um, ul);
        W1h[t] = (unsigned short)(uh >> 16);
        W1m[t] = (unsigned short)(um >> 16);
        W1l[t] = (unsigned short)(ul >> 16);
    } else {
        const int t2 = t - 65536;
        const int j = t2 & 7, lane = (t2 >> 3) & 63, nt = (t2 >> 9) & 7,
                  kt = (t2 >> 12) & 15;
        const int k = kt * 32 + (lane >> 4) * 8 + j;
        const int n = nt * 16 + (lane & 15);
        split3(W2[k * 128 + n], uh, um, ul);
        W2h[t2] = (unsigned short)(uh >> 16);
        W2m[t2] = (unsigned short)(um >> 16);
        W2l[t2] = (unsigned short)(ul >> 16);
    }
}

// 6-term bf16x3 MFMA accumulate (small terms first); error ~2^-24
#define MFMA6(AH, AM, AL, BH, BM, BL, ACC)                                    \
    ACC = __builtin_amdgcn_mfma_f32_16x16x32_bf16(AL, BH, ACC, 0, 0, 0);      \
    ACC = __builtin_amdgcn_mfma_f32_16x16x32_bf16(AM, BM, ACC, 0, 0, 0);      \
    ACC = __builtin_amdgcn_mfma_f32_16x16x32_bf16(AH, BL, ACC, 0, 0, 0);      \
    ACC = __builtin_amdgcn_mfma_f32_16x16x32_bf16(AM, BH, ACC, 0, 0, 0);      \
    ACC = __builtin_amdgcn_mfma_f32_16x16x32_bf16(AH, BM, ACC, 0, 0, 0);      \
    ACC = __builtin_amdgcn_mfma_f32_16x16x32_bf16(AH, BH, ACC, 0, 0, 0);

// XOR-swizzled LDS address: rows x 128 cols of ushort,
// addr = row*128 + ((chunk ^ (row&15))<<3) + (col&7), chunk = col>>3.
__device__ __forceinline__ int swz(int row, int col) {
    return row * 128 + ((((col >> 3) ^ (row & 15))) << 3) + (col & 7);
}

// ---------------- fused MLP (+ previous step's DPM update when UPD) --------
// R6: M=64 (4 l-rows), grid 256 (1 block/CU), 512 thr (8 waves),
// launch_bounds(512,2) -> up to 256 VGPR. Rationale (R4/R5 post-mortem):
// VGPR 60->32 with more waves made mlp WORSE; the constraint is per-wave
// pipelining depth, not occupancy. Fat waves: acc1[16] (4 M-tiles x 4 q),
// 24 MFMA per W-fragment triple (2x R4), W logical traffic halved
// (256 x 768KB = 192MB), ~48 VGPR of A-frags reused across 4 q.
template <int UPD>
__global__ __launch_bounds__(512, 2) void mlp_kernel(
    float* __restrict__ z, const float* __restrict__ zr,
    const float* __restrict__ y, const float* __restrict__ mk,
    const unsigned short* __restrict__ W1h, const unsigned short* __restrict__ W1m,
    const unsigned short* __restrict__ W1l, const unsigned short* __restrict__ W2h,
    const unsigned short* __restrict__ W2m, const unsigned short* __restrict__ W2l,
    const float* __restrict__ b1, const float* __restrict__ tw,
    const float* __restrict__ b2, float t_feat,
    float* __restrict__ eps_buf, float* __restrict__ ent,
    const float* __restrict__ cA, const float* __restrict__ cB,
    const float* __restrict__ cG, float* __restrict__ accum) {
    __shared__ unsigned short zA[3][8192];  // swizzled [row<64][col<128]
    __shared__ unsigned short hA[3][8192];  // swizzled h quarter, M=64
    __shared__ float red1[8], red2[8];
    const int tid = threadIdx.x;
    const int w = tid >> 6, lane = tid & 63;  // w = 0..7
    const int quad = lane >> 4, m16 = lane & 15;
    const int l0 = blockIdx.x * 4;

    // ---- phase 1: (coeff-map update) + stats + stage split z into LDS ----
    float s1 = 0.f, s2 = 0.f;
#pragma unroll
    for (int e = 0; e < 4; ++e) {
        const int f = (e * 512 + tid) * 4;  // 0..8188, coalesced per e
        const int r_ = f >> 7, cb = f & 127;
        const int b = r_ & 15, il = r_ >> 4, l = l0 + il;
        const size_t g = ((size_t)b * 1024 + l) * 128 + cb;
        float4 zv = *(const float4*)(zr + g);
        const float4 yv = *(const float4*)(y + g);
        const float4 mv = *(const float4*)(mk + g);
        if (UPD) {
            const float4 ev = *(const float4*)(eps_buf + g);
            const int pix = l * 128 + cb;
            const float4 a4 = *(const float4*)(cA + pix);
            const float4 b4 = *(const float4*)(cB + pix);
            const float4 g4 = *(const float4*)(cG + pix);
            zv.x = a4.x * zv.x - b4.x * ev.x - g4.x * ((zv.x - yv.x) * mv.x);
            zv.y = a4.y * zv.y - b4.y * ev.y - g4.y * ((zv.y - yv.y) * mv.y);
            zv.z = a4.z * zv.z - b4.z * ev.z - g4.z * ((zv.z - yv.z) * mv.z);
            zv.w = a4.w * zv.w - b4.w * ev.w - g4.w * ((zv.w - yv.w) * mv.w);
            *(float4*)(z + g) = zv;
        }
        float oe;
        oe = (zv.x - yv.x) * mv.x; s1 += oe; s2 += oe * oe;
        oe = (zv.y - yv.y) * mv.y; s1 += oe; s2 += oe * oe;
        oe = (zv.z - yv.z) * mv.z; s1 += oe; s2 += oe * oe;
        oe = (zv.w - yv.w) * mv.w; s1 += oe; s2 += oe * oe;

        // swizzled staging (ushort4 = 8B per array; conflict-free)
        const int base = swz(r_, cb);
        const float xs[4] = {zv.x, zv.y, zv.z, zv.w};
        ushort4 vh, vm, vl;
        unsigned uh, um, ul;
        split3(xs[0], uh, um, ul); vh.x = uh >> 16; vm.x = um >> 16; vl.x = ul >> 16;
        split3(xs[1], uh, um, ul); vh.y = uh >> 16; vm.y = um >> 16; vl.y = ul >> 16;
        split3(xs[2], uh, um, ul); vh.z = uh >> 16; vm.z = um >> 16; vl.z = ul >> 16;
        split3(xs[3], uh, um, ul); vh.w = uh >> 16; vm.w = um >> 16; vl.w = ul >> 16;
        *(ushort4*)(&zA[0][base]) = vh;
        *(ushort4*)(&zA[1][base]) = vm;
        *(ushort4*)(&zA[2][base]) = vl;
    }
#pragma unroll
    for (int off = 32; off; off >>= 1) {
        s1 += __shfl_down(s1, off);
        s2 += __shfl_down(s2, off);
    }
    if (lane == 0) { red1[w] = s1; red2[w] = s2; }
    __syncthreads();  // staging + red complete
    if (tid == 0) {
        float a1 = 0.f, a2 = 0.f;
#pragma unroll
        for (int i = 0; i < 8; ++i) { a1 += red1[i]; a2 += red2[i]; }
        atomicAdd(&accum[0], a1);
        atomicAdd(&accum[1], a2);
    }

    // ---- GEMM1 (all H): acc1[q*4+il], wave's nt = q*8 + w ----
    floatx4 acc1[16];
#pragma unroll
    for (int i = 0; i < 16; ++i) acc1[i] = (floatx4){0.f, 0.f, 0.f, 0.f};

#pragma unroll
    for (int kt = 0; kt < 4; ++kt) {
        short8 Ah[4], Am[4], Al[4];
#pragma unroll
        for (int il = 0; il < 4; ++il) {
            const int fb = swz(il * 16 + m16, kt * 32 + quad * 8);
            Ah[il] = *(const short8*)(&zA[0][fb]);
            Am[il] = *(const short8*)(&zA[1][fb]);
            Al[il] = *(const short8*)(&zA[2][fb]);
        }
#pragma unroll
        for (int q = 0; q < 4; ++q) {
            const size_t off = ((size_t)(kt * 32 + q * 8 + w) * 64 + lane) * 8;
            const short8 bh = *(const short8*)(W1h + off);
            const short8 bm = *(const short8*)(W1m + off);
            const short8 bl = *(const short8*)(W1l + off);
#pragma unroll
            for (int il = 0; il < 4; ++il) {
                floatx4 a = acc1[q * 4 + il];
                MFMA6(Ah[il], Am[il], Al[il], bh, bm, bl, a);
                acc1[q * 4 + il] = a;
            }
        }
    }

    // ---- quarter phases: gelu+split h -> hA, GEMM2 partial-K ----
    floatx4 acc2[4];
#pragma unroll
    for (int i = 0; i < 4; ++i) acc2[i] = (floatx4){0.f, 0.f, 0.f, 0.f};

#pragma unroll
    for (int q = 0; q < 4; ++q) {
        {
            const int colg = q * 128 + w * 16 + m16;
            const float bb = b1[colg] + t_feat * tw[colg];
            const int kcol = w * 16 + m16;  // quarter-local k col
#pragma unroll
            for (int il = 0; il < 4; ++il) {
#pragma unroll
                for (int r = 0; r < 4; ++r) {
                    const float x = gelu_fast(acc1[q * 4 + il][r] + bb);
                    unsigned uh, um, ul;
                    split3(x, uh, um, ul);
                    const int idx = swz(il * 16 + quad * 4 + r, kcol);
                    hA[0][idx] = (unsigned short)(uh >> 16);
                    hA[1][idx] = (unsigned short)(um >> 16);
                    hA[2][idx] = (unsigned short)(ul >> 16);
                }
            }
        }
        __syncthreads();  // hA writes visible (hA separate from zA)

#pragma unroll
        for (int ktl = 0; ktl < 4; ++ktl) {
            short8 Ah2[4], Am2[4], Al2[4];
#pragma unroll
            for (int il = 0; il < 4; ++il) {
                const int fb = swz(il * 16 + m16, ktl * 32 + quad * 8);
                Ah2[il] = *(const short8*)(&hA[0][fb]);
                Am2[il] = *(const short8*)(&hA[1][fb]);
                Al2[il] = *(const short8*)(&hA[2][fb]);
            }
            const size_t off =
                ((size_t)((q * 4 + ktl) * 8 + w) * 64 + lane) * 8;
            const short8 bh = *(const short8*)(W2h + off);
            const short8 bm = *(const short8*)(W2m + off);
            const short8 bl = *(const short8*)(W2l + off);
#pragma unroll
            for (int il = 0; il < 4; ++il) {
                floatx4 a = acc2[il];
                MFMA6(Ah2[il], Am2[il], Al2[il], bh, bm, bl, a);
                acc2[il] = a;
            }
        }
        __syncthreads();  // all hA reads done before next quarter's write
    }

    // ---- epilogue: +b2, write eps, ent = mean_b |eps| ----
    {
        const int col = w * 16 + m16;
        const float bb2 = b2[col];
#pragma unroll
        for (int il = 0; il < 4; ++il) {
            float pa = 0.f;
#pragma unroll
            for (int r = 0; r < 4; ++r) {
                const float e = acc2[il][r] + bb2;
                const int b = quad * 4 + r;
                eps_buf[((size_t)b * 1024 + l0 + il) * 128 + col] = e;
                pa += fabsf(e);
            }
            pa += __shfl_xor(pa, 16);
            pa += __shfl_xor(pa, 32);
            if (quad == 0) ent[(l0 + il) * 128 + col] = pa * (1.0f / 16.0f);
        }
    }
}

// ======================= select path, barrier-free =========================
// Kernel boundaries are the global barriers; all cross-kernel reads are
// plain loads.

// ---- S1: pools (proven summation order) + 14-bit fordbits hist (scale 0) --
__global__ __launch_bounds__(256) void pools_kernel(
    const float* __restrict__ ent, float* __restrict__ p1,
    float* __restrict__ p2, float* __restrict__ p3,
    unsigned* __restrict__ ghist) {
    __shared__ unsigned lh[8192];
    const int tid = threadIdx.x;
    const int gid = blockIdx.x * 256 + tid;  // < 65536
    for (int i = tid; i < 8192; i += 256) lh[i] = 0u;
    __syncthreads();

    // ent histogram (scale 0): 2 elements/thread into packed block hist
    {
        const float2 ev = *(const float2*)(ent + (size_t)gid * 2);
        const unsigned b0 = fordbits(__float_as_uint(ev.x)) >> 18;
        const unsigned b1_ = fordbits(__float_as_uint(ev.y)) >> 18;
        atomicAdd(&lh[b0 >> 1], 1u << ((b0 & 1) << 4));
        atomicAdd(&lh[b1_ >> 1], 1u << ((b1_ & 1) << 4));
    }
    // p1: w=2, 512x64
    if (gid < 32768) {
        const int r = gid >> 6, c = gid & 63;
        float s = 0.f;
#pragma unroll
        for (int ii = 0; ii < 2; ++ii) {
            const float2 e = *(const float2*)(ent + (((r * 2 + ii) << 7) + c * 2));
            s += e.x; s += e.y;
        }
        p1[gid] = s * 0.25f;
    }
    // p2: w=4, 256x32
    if (gid < 8192) {
        const int r = gid >> 5, c = gid & 31;
        float s = 0.f;
#pragma unroll
        for (int ii = 0; ii < 4; ++ii) {
            const float4 e = *(const float4*)(ent + (((r * 4 + ii) << 7) + c * 4));
            s += e.x; s += e.y; s += e.z; s += e.w;
        }
        p2[gid] = s * 0.0625f;
    }
    // p3: w=8, 128x16
    if (gid < 2048) {
        const int r = gid >> 4, c = gid & 15;
        float s = 0.f;
#pragma unroll
        for (int ii = 0; ii < 8; ++ii) {
            const float4 ea = *(const float4*)(ent + (((r * 8 + ii) << 7) + c * 8));
            const float4 eb = *(const float4*)(ent + (((r * 8 + ii) << 7) + c * 8 + 4));
            s += ea.x; s += ea.y; s += ea.z; s += ea.w;
            s += eb.x; s += eb.y; s += eb.z; s += eb.w;
        }
        p3[gid] = s * (1.0f / 64.0f);
    }
    __syncthreads();
    // merge packed nonzero bins to global
    for (int i = tid; i < 8192; i += 256) {
        const unsigned v = lh[i];
        if (v & 0xFFFFu) atomicAdd(&ghist[2 * i], v & 0xFFFFu);
        if (v >> 16) atomicAdd(&ghist[2 * i + 1], v >> 16);
    }
}

#define CAND_CAP 16384

// ---- register-resident exact Kth-largest for small pools (scales 1..3) ----
template <int NPT4, int N, unsigned K>
__device__ __forceinline__ void small_select(
    const float* __restrict__ data, unsigned* __restrict__ gout, const int t,
    const int w8, unsigned* __restrict__ histcand,
    unsigned* __restrict__ part, unsigned (*hrep)[512],
    unsigned* sh_b, unsigned* sh_krem, unsigned* sh_cnt, unsigned* sh_d,
    unsigned* sh_k2) {
    // batched vector load into registers (phantom -1e30 < all real values)
    float4 xv[NPT4];
#pragma unroll
    for (int i = 0; i < NPT4; ++i) {
        const int idx4 = t + i * 1024;
        if (idx4 < (N >> 2)) xv[i] = ((const float4*)data)[idx4];
        else xv[i] = (float4){-1e30f, -1e30f, -1e30f, -1e30f};
    }
    unsigned u[NPT4 * 4];
#pragma unroll
    for (int i = 0; i < NPT4; ++i) {
        u[4 * i + 0] = fordbits(__float_as_uint(xv[i].x));
        u[4 * i + 1] = fordbits(__float_as_uint(xv[i].y));
        u[4 * i + 2] = fordbits(__float_as_uint(xv[i].z));
        u[4 * i + 3] = fordbits(__float_as_uint(xv[i].w));
    }
    if (t == 0) { *sh_b = 0u; *sh_krem = 1u; *sh_cnt = 0u; *sh_d = 0u; *sh_k2 = 1u; }
    for (int i = t; i < 16384; i += 1024) histcand[i] = 0u;
    __syncthreads();
#pragma unroll
    for (int j = 0; j < NPT4 * 4; ++j) atomicAdd(&histcand[u[j] >> 18], 1u);
    __syncthreads();
    // suffix scan over 16384 bins: 16/thread, then 1024-block scan
    {
        unsigned s = 0;
#pragma unroll
        for (int j = 0; j < 16; ++j) s += histcand[t * 16 + j];
        part[t] = s;
    }
    __syncthreads();
    for (int off = 1; off < 1024; off <<= 1) {
        const unsigned v = (t + off < 1024) ? part[t + off] : 0u;
        __syncthreads();
        part[t] += v;
        __syncthreads();
    }
    {
        const unsigned suf = part[t];
        const unsigned sufn = (t < 1023) ? part[t + 1] : 0u;
        if (suf >= K && sufn < K) {
            unsigned run = sufn;
            for (int b = 15; b >= 0; --b) {
                const unsigned hb = histcand[t * 16 + b];
                run += hb;
                if (run >= K) {
                    *sh_b = (unsigned)(t * 16 + b);
                    *sh_krem = K - (run - hb);
                    break;
                }
            }
        }
    }
    __syncthreads();
    const unsigned b14 = *sh_b;
    unsigned krem = *sh_krem;
    __syncthreads();  // all histcand reads done before cand overwrite
    // compact candidates from registers into histcand-as-cand
#pragma unroll
    for (int j = 0; j < NPT4 * 4; ++j)
        if ((u[j] >> 18) == b14) {
            const unsigned p = atomicAdd(sh_cnt, 1u);
            if (p < CAND_CAP) histcand[p] = u[j];
        }
    __syncthreads();
    const unsigned cnt = *sh_cnt;
    const bool inlds = (cnt <= CAND_CAP);
    // ---- refine bits 17..9 ----
    for (int i = t; i < 4096; i += 1024) ((unsigned*)hrep)[i] = 0u;
    __syncthreads();
    if (inlds) {
        for (unsigned i = t; i < cnt; i += 1024)
            atomicAdd(&hrep[w8][(histcand[i] >> 9) & 511u], 1u);
    } else {
#pragma unroll
        for (int j = 0; j < NPT4 * 4; ++j)
            if ((u[j] >> 18) == b14)
                atomicAdd(&hrep[w8][(u[j] >> 9) & 511u], 1u);
    }
    __syncthreads();
    if (t < 512) {
        unsigned s = 0;
#pragma unroll
        for (int r = 0; r < 8; ++r) s += hrep[r][t];
        part[t] = s;
    }
    __syncthreads();
    for (int off = 1; off < 512; off <<= 1) {
        unsigned v = 0u;
        if (t < 512) v = (t + off < 512) ? part[t + off] : 0u;
        __syncthreads();
        if (t < 512) part[t] += v;
        __syncthreads();
    }
    if (t < 512) {
        const unsigned suf = part[t];
        const unsigned sufn = (t < 511) ? part[t + 1] : 0u;
        if (suf >= krem && sufn < krem) { *sh_d = (unsigned)t; *sh_k2 = krem - sufn; }
    }
    __syncthreads();
    const unsigned dA = *sh_d;
    krem = *sh_k2;
    __syncthreads();
    // ---- refine bits 8..0 ----
    for (int i = t; i < 4096; i += 1024) ((unsigned*)hrep)[i] = 0u;
    __syncthreads();
    if (inlds) {
        for (unsigned i = t; i < cnt; i += 1024) {
            const unsigned c = histcand[i];
            if (((c >> 9) & 511u) == dA) atomicAdd(&hrep[w8][c & 511u], 1u);
        }
    } else {
#pragma unroll
        for (int j = 0; j < NPT4 * 4; ++j)
            if ((u[j] >> 18) == b14 && ((u[j] >> 9) & 511u) == dA)
                atomicAdd(&hrep[w8][u[j] & 511u], 1u);
    }
    __syncthreads();
    if (t < 512) {
        unsigned s = 0;
#pragma unroll
        for (int r = 0; r < 8; ++r) s += hrep[r][t];
        part[t] = s;
    }
    __syncthreads();
    for (int off = 1; off < 512; off <<= 1) {
        unsigned v = 0u;
        if (t < 512) v = (t + off < 512) ? part[t + off] : 0u;
        __syncthreads();
        if (t < 512) part[t] += v;
        __syncthreads();
    }
    if (t < 512) {
        const unsigned suf = part[t];
        const unsigned sufn = (t < 511) ? part[t + 1] : 0u;
        if (suf >= krem && sufn < krem)
            gout[0] = (b14 << 18) | (dA << 9) | (unsigned)t;
    }
}

// ---- S2: exact K-th-largest thresholds. 4 blocks x 1024 thr (1/scale). ----
__global__ __launch_bounds__(1024, 1) void thresh_kernel(
    const float* __restrict__ ent, const float* __restrict__ p1,
    const float* __restrict__ p2, const float* __restrict__ p3,
    const unsigned* __restrict__ ghist, unsigned* __restrict__ gprefix) {
    const int scale = blockIdx.x, t = threadIdx.x;
    __shared__ unsigned histcand[16384];  // 14-bit hist, then candidates
    __shared__ unsigned part[1024];
    __shared__ unsigned hrep[8][512];
    __shared__ unsigned sh_b, sh_krem, sh_cnt, sh_d, sh_k2;
    const int w8 = (t >> 6) & 7;

    if (scale == 1) {
        small_select<8, 32768, 6553u>(p1, &gprefix[1], t, w8, histcand, part,
                                      hrep, &sh_b, &sh_krem, &sh_cnt, &sh_d,
                                      &sh_k2);
        return;
    }
    if (scale == 2) {
        small_select<2, 8192, 1638u>(p2, &gprefix[2], t, w8, histcand, part,
                                     hrep, &sh_b, &sh_krem, &sh_cnt, &sh_d,
                                     &sh_k2);
        return;
    }
    if (scale == 3) {
        small_select<1, 2048, 409u>(p3, &gprefix[3], t, w8, histcand, part,
                                    hrep, &sh_b, &sh_krem, &sh_cnt, &sh_d,
                                    &sh_k2);
        return;
    }

    // ---------------- scale 0: ent, N=131072, K=26214 ----------------
    const unsigned K = 26214u;
    if (t == 0) { sh_b = 0u; sh_krem = 1u; sh_cnt = 0u; sh_d = 0u; sh_k2 = 1u; }

    // 14-bit bucket from global hist: 16 bins/thread + block suffix scan
    {
        unsigned s = 0;
        const uint4* h4 = (const uint4*)(ghist + t * 16);
#pragma unroll
        for (int j = 0; j < 4; ++j) {
            const uint4 x = h4[j];
            s += x.x + x.y + x.z + x.w;
        }
        part[t] = s;
    }
    __syncthreads();
    for (int off = 1; off < 1024; off <<= 1) {
        const unsigned v = (t + off < 1024) ? part[t + off] : 0u;
        __syncthreads();
        part[t] += v;
        __syncthreads();
    }
    {
        const unsigned suf = part[t];
        const unsigned sufn = (t < 1023) ? part[t + 1] : 0u;
        if (suf >= K && sufn < K) {  // unique crossing chunk
            unsigned run = sufn;
            for (int b = 15; b >= 0; --b) {
                const unsigned hb = ghist[t * 16 + b];
                run += hb;
                if (run >= K) {
                    sh_b = (unsigned)(t * 16 + b);
                    sh_krem = K - (run - hb);
                    break;
                }
            }
        }
    }
    __syncthreads();
    const unsigned b14 = sh_b;
    unsigned krem = sh_krem;

    // compact in-bucket candidates into LDS; batched 8x float4 loads
    for (int base = 0; base < 32768; base += 8192) {
        float4 w4[8];
#pragma unroll
        for (int i = 0; i < 8; ++i)
            w4[i] = ((const float4*)ent)[base + i * 1024 + t];
#pragma unroll
        for (int i = 0; i < 8; ++i) {
            const float xs[4] = {w4[i].x, w4[i].y, w4[i].z, w4[i].w};
#pragma unroll
            for (int j = 0; j < 4; ++j) {
                const unsigned uu = fordbits(__float_as_uint(xs[j]));
                if ((uu >> 18) == b14) {
                    const unsigned p = atomicAdd(&sh_cnt, 1u);
                    if (p < CAND_CAP) histcand[p] = uu;
                }
            }
        }
    }
    __syncthreads();
    const unsigned cnt = sh_cnt;
    const bool inlds = (cnt <= CAND_CAP);

    // ---- refine bits 17..9 ----
    for (int i = t; i < 4096; i += 1024) ((unsigned*)hrep)[i] = 0u;
    __syncthreads();
    if (inlds) {
        for (unsigned i = t; i < cnt; i += 1024)
            atomicAdd(&hrep[w8][(histcand[i] >> 9) & 511u], 1u);
    } else {
        for (int base = 0; base < 32768; base += 8192) {
            float4 w4[8];
#pragma unroll
            for (int i = 0; i < 8; ++i)
                w4[i] = ((const float4*)ent)[base + i * 1024 + t];
#pragma unroll
            for (int i = 0; i < 8; ++i) {
                const float xs[4] = {w4[i].x, w4[i].y, w4[i].z, w4[i].w};
#pragma unroll
                for (int j = 0; j < 4; ++j) {
                    const unsigned uu = fordbits(__float_as_uint(xs[j]));
                    if ((uu >> 18) == b14)
                        atomicAdd(&hrep[w8][(uu >> 9) & 511u], 1u);
                }
            }
        }
    }
    __syncthreads();
    if (t < 512) {
        unsigned s = 0;
#pragma unroll
        for (int r = 0; r < 8; ++r) s += hrep[r][t];
        part[t] = s;
    }
    __syncthreads();
    for (int off = 1; off < 512; off <<= 1) {
        unsigned v = 0u;
        if (t < 512) v = (t + off < 512) ? part[t + off] : 0u;
        __syncthreads();
        if (t < 512) part[t] += v;
        __syncthreads();
    }
    if (t < 512) {
        const unsigned suf = part[t];
        const unsigned sufn = (t < 511) ? part[t + 1] : 0u;
        if (suf >= krem && sufn < krem) { sh_d = (unsigned)t; sh_k2 = krem - sufn; }
    }
    __syncthreads();
    const unsigned dA = sh_d;
    krem = sh_k2;
    __syncthreads();

    // ---- refine bits 8..0 ----
    for (int i = t; i < 4096; i += 1024) ((unsigned*)hrep)[i] = 0u;
    __syncthreads();
    if (inlds) {
        for (unsigned i = t; i < cnt; i += 1024) {
            const unsigned c = histcand[i];
            if (((c >> 9) & 511u) == dA) atomicAdd(&hrep[w8][c & 511u], 1u);
        }
    } else {
        for (int base = 0; base < 32768; base += 8192) {
            float4 w4[8];
#pragma unroll
            for (int i = 0; i < 8; ++i)
                w4[i] = ((const float4*)ent)[base + i * 1024 + t];
#pragma unroll
            for (int i = 0; i < 8; ++i) {
                const float xs[4] = {w4[i].x, w4[i].y, w4[i].z, w4[i].w};
#pragma unroll
                for (int j = 0; j < 4; ++j) {
                    const unsigned uu = fordbits(__float_as_uint(xs[j]));
                    if ((uu >> 18) == b14 && ((uu >> 9) & 511u) == dA)
                        atomicAdd(&hrep[w8][uu & 511u], 1u);
                }
            }
        }
    }
    __syncthreads();
    if (t < 512) {
        unsigned s = 0;
#pragma unroll
        for (int r = 0; r < 8; ++r) s += hrep[r][t];
        part[t] = s;
    }
    __syncthreads();
    for (int off = 1; off < 512; off <<= 1) {
        unsigned v = 0u;
        if (t < 512) v = (t + off < 512) ? part[t + off] : 0u;
        __syncthreads();
        if (t < 512) part[t] += v;
        __syncthreads();
    }
    if (t < 512) {
        const unsigned suf = part[t];
        const unsigned sufn = (t < 511) ? part[t + 1] : 0u;
        if (suf >= krem && sufn < krem)
            gprefix[0] = (b14 << 18) | (dA << 9) | (unsigned)t;
    }
}

// ---- S3: per-pixel coeff maps, plain streaming loads; zeroes hist next ----
__global__ __launch_bounds__(256) void coeff_kernel(
    const float* __restrict__ ent, const float* __restrict__ p1,
    const float* __restrict__ p2, const float* __restrict__ p3,
    const unsigned* __restrict__ gprefix, const float* __restrict__ accum_si,
    float* __restrict__ cA, float* __restrict__ cB, float* __restrict__ cG,
    unsigned* __restrict__ ghist, float base_a, float base_b, float h_lam) {
    const int i = blockIdx.x * 256 + threadIdx.x;  // < 131072
    // zero 14-bit histogram for the next step's pools_kernel
    if (i < 16384) ghist[i] = 0u;

    const unsigned t0 = gprefix[0], t1 = gprefix[1], t2 = gprefix[2],
                   t3 = gprefix[3];
    const float mean = accum_si[0] * (1.0f / (float)BLC);
    const float var = accum_si[1] * (1.0f / (float)BLC) - mean * mean;
    const float vinv = 1.0f / (var + 1e-8f);

    const int l = i >> 7, c = i & 127;
    float ent_v = 0.f;
    bool sel = false;
    const float v0 = ent[i];
    if (fordbits(__float_as_uint(v0)) >= t0) { ent_v = v0; sel = true; }
    else {
        const float v1 = p1[((l >> 1) << 6) + (c >> 1)];
        if (fordbits(__float_as_uint(v1)) >= t1) { ent_v = v1; sel = true; }
        else {
            const float v2 = p2[((l >> 2) << 5) + (c >> 2)];
            if (fordbits(__float_as_uint(v2)) >= t2) { ent_v = v2; sel = true; }
            else {
                const float v3 = p3[((l >> 3) << 4) + (c >> 3)];
                if (fordbits(__float_as_uint(v3)) >= t3) { ent_v = v3; sel = true; }
            }
        }
    }
    if (sel) {
        float corr;
        if (ent_v > 0.5f)
            corr = 1.0f + h_lam + h_lam * h_lam * (1.0f / 3.0f);
        else if (ent_v > 0.1f)
            corr = 1.0f + 0.5f * h_lam;
        else
            corr = 1.0f;
        cA[i] = base_a;
        cB[i] = base_b * corr;
        cG[i] = (2.0f * ent_v / (ent_v + 1.0f)) * vinv;
    } else {
        cA[i] = 1.0f;
        cB[i] = 0.f;
        cG[i] = 0.f;
    }
}

// ---------------- standalone final update (coeff-map streaming) ------------
__global__ __launch_bounds__(256) void update_kernel(
    float* __restrict__ z, const float* __restrict__ y,
    const float* __restrict__ mk, const float* __restrict__ eps,
    const float* __restrict__ cA, const float* __restrict__ cB,
    const float* __restrict__ cG) {
    const int idx = blockIdx.x * 256 + threadIdx.x;  // < BLC
    const int p = idx & (LC - 1);
    const float zi = z[idx];
    z[idx] = cA[p] * zi - cB[p] * eps[idx] - cG[p] * ((zi - y[idx]) * mk[idx]);
}

// ---------------------------------------------------------------------------
extern "C" void kernel_launch(void* const* d_in, const int* in_sizes, int n_in,
                              void* d_out, int out_size, void* d_ws,
                              size_t ws_size, hipStream_t stream) {
    const float* y_obs = (const float*)d_in[0];
    const float* mask = (const float*)d_in[1];
    const float* z_init = (const float*)d_in[2];
    const float* W1 = (const float*)d_in[3];
    const float* b1 = (const float*)d_in[4];
    const float* W2 = (const float*)d_in[5];
    const float* b2 = (const float*)d_in[6];
    const float* tw = (const float*)d_in[7];
    float* z = (float*)d_out;
    float* ws = (float*)d_ws;

    // workspace layout (float offsets); end = 2877452 floats = 11,509,808 B
    float* eps = ws;                                 // 2097152
    float* ent = ws + 2097152;                       // 131072
    float* p1 = ws + 2228224;                        // 32768
    float* p2 = ws + 2260992;                        // 8192
    float* p3 = ws + 2269184;                        // 2048
    float* cA = ws + 2271232;                        // 131072
    float* cB = ws + 2402304;                        // 131072
    float* cG = ws + 2533376;                        // 131072
    // zero block: accum[8] | gprefix[4] | ghist[16384] (contig 16396 u32)
    float* accum = ws + 2664448;                     // 8 (2 per step)
    unsigned* gprefix = (unsigned*)(ws + 2664456);   // 4
    unsigned* ghist = (unsigned*)(ws + 2664460);     // 16384 u32
    unsigned short* W1h = (unsigned short*)(ws + 2680844);  // 65536 u16 each
    unsigned short* W1m = (unsigned short*)(ws + 2713612);
    unsigned short* W1l = (unsigned short*)(ws + 2746380);
    unsigned short* W2h = (unsigned short*)(ws + 2779148);
    unsigned short* W2m = (unsigned short*)(ws + 2811916);
    unsigned short* W2l = (unsigned short*)(ws + 2844684);

    // diffusion schedule in fp32 (input-independent)
    float alpha_[1000], sigma_[1000], lam_[1000];
    {
        float ac = 1.0f;
        for (int i = 0; i < 1000; ++i) {
            const float beta = 1e-4f + (0.02f - 1e-4f) * ((float)i / 999.0f);
            ac = ac * (1.0f - beta);
            alpha_[i] = sqrtf(ac);
            sigma_[i] = sqrtf(1.0f - ac);
            lam_[i] = logf(alpha_[i]) - logf(sigma_[i]);
        }
    }
    float tf[4], hl[4], ba[4], bb[4];
    for (int si = 0; si < 4; ++si) {
        const int k = 999 - si * 250;
        const int kp = (k - 250 > 0) ? (k - 250) : 0;
        tf[si] = (float)k / 1000.0f;
        hl[si] = lam_[kp] - lam_[k];
        ba[si] = alpha_[kp] / alpha_[k];
        bb[si] = sigma_[kp] * (expf(hl[si]) - 1.0f);
    }

    // wsplit also zeroes accum|gprefix|ghist every launch/replay
    wsplit_kernel<<<512, 256, 0, stream>>>(W1, W2, W1h, W1m, W1l, W2h, W2m,
                                           W2l, (unsigned*)accum);

    for (int si = 0; si < 4; ++si) {
        // z is first WRITTEN at si=1; si=0,1 read z_init directly (no memcpy)
        const float* zrd = (si <= 1) ? z_init : z;
        if (si == 0) {
            mlp_kernel<0><<<256, 512, 0, stream>>>(
                z, zrd, y_obs, mask, W1h, W1m, W1l, W2h, W2m, W2l, b1, tw, b2,
                tf[0], eps, ent, cA, cB, cG, accum);
        } else {
            mlp_kernel<1><<<256, 512, 0, stream>>>(
                z, zrd, y_obs, mask, W1h, W1m, W1l, W2h, W2m, W2l, b1, tw, b2,
                tf[si], eps, ent, cA, cB, cG, accum + 2 * si);
        }
        pools_kernel<<<256, 256, 0, stream>>>(ent, p1, p2, p3, ghist);
        thresh_kernel<<<4, 1024, 0, stream>>>(ent, p1, p2, p3, ghist, gprefix);
        coeff_kernel<<<512, 256, 0, stream>>>(ent, p1, p2, p3, gprefix,
                                              accum + 2 * si, cA, cB, cG,
                                              ghist, ba[si], bb[si], hl[si]);
    }
    update_kernel<<<8192, 256, 0, stream>>>(z, y_obs, mask, eps, cA, cB, cG);
}

// Round 7
// 366.720 us; speedup vs baseline: 1.1340x; 1.0476x over previous
//
#include <hip/hip_runtime.h>
#include <math.h>
#include <stdint.h>

#define L_DIM 1024
#define C_DIM 128
#define H_DIM 512
#define B_DIM 16
#define LC (L_DIM * C_DIM)      // 131072
#define BLC (B_DIM * LC)        // 2097152

typedef __attribute__((ext_vector_type(8))) short short8;
typedef __attribute__((ext_vector_type(4))) float floatx4;

// ---------------- monotone float/bits -> ordered uint ----------------------
__device__ __forceinline__ unsigned fordbits(unsigned u) {
    return (u & 0x80000000u) ? ~u : (u | 0x80000000u);
}

// ---------------- truncation 3-way bf16 split: x = h + m + l + O(2^-24 x) --
__device__ __forceinline__ void split3(float x, unsigned& uh, unsigned& um,
                                       unsigned& ul) {
    uh = __float_as_uint(x);
    const float r1 = x - __uint_as_float(uh & 0xffff0000u);
    um = __float_as_uint(r1);
    const float r2 = r1 - __uint_as_float(um & 0xffff0000u);
    ul = __float_as_uint(r2);
}

__device__ __forceinline__ float gelu_fast(float x) {
    const float g = 0.7978845608028654f * (x + 0.044715f * x * x * x);
    const float e = __expf(2.0f * g);
    const float t = 1.0f - 2.0f / (e + 1.0f);
    return 0.5f * x * (1.0f + t);
}

// ---------------- W pre-split into MFMA B-frag layout (h/m/l bf16) ---------
// Also zeroes the accum|gprefix|ghist block (16396 u32) every launch/replay.
__global__ __launch_bounds__(256) void wsplit_kernel(
    const float* __restrict__ W1, const float* __restrict__ W2,
    unsigned short* __restrict__ W1h, unsigned short* __restrict__ W1m,
    unsigned short* __restrict__ W1l, unsigned short* __restrict__ W2h,
    unsigned short* __restrict__ W2m, unsigned short* __restrict__ W2l,
    unsigned* __restrict__ zeroblk) {
    const int t = blockIdx.x * 256 + threadIdx.x;  // < 131072
    if (t < 16396) zeroblk[t] = 0u;
    unsigned uh, um, ul;
    if (t < 65536) {
        const int j = t & 7, lane = (t >> 3) & 63, nt = (t >> 9) & 31,
                  kt = (t >> 14) & 3;
        const int k = kt * 32 + (lane >> 4) * 8 + j;
        const int n = nt * 16 + (lane & 15);
        split3(W1[k * 512 + n], uh, um, ul);
        W1h[t] = (unsigned short)(uh >> 16);
        W1m[t] = (unsigned short)(um >> 16);
        W1l[t] = (unsigned short)(ul >> 16);
    } else {
        const int t2 = t - 65536;
        const int j = t2 & 7, lane = (t2 >> 3) & 63, nt = (t2 >> 9) & 7,
                  kt = (t2 >> 12) & 15;
        const int k = kt * 32 + (lane >> 4) * 8 + j;
        const int n = nt * 16 + (lane & 15);
        split3(W2[k * 128 + n], uh, um, ul);
        W2h[t2] = (unsigned short)(uh >> 16);
        W2m[t2] = (unsigned short)(um >> 16);
        W2l[t2] = (unsigned short)(ul >> 16);
    }
}

// 6-term bf16x3 MFMA accumulate (small terms first); error ~2^-24
#define MFMA6(AH, AM, AL, BH, BM, BL, ACC)                                    \
    ACC = __builtin_amdgcn_mfma_f32_16x16x32_bf16(AL, BH, ACC, 0, 0, 0);      \
    ACC = __builtin_amdgcn_mfma_f32_16x16x32_bf16(AM, BM, ACC, 0, 0, 0);      \
    ACC = __builtin_amdgcn_mfma_f32_16x16x32_bf16(AH, BL, ACC, 0, 0, 0);      \
    ACC = __builtin_amdgcn_mfma_f32_16x16x32_bf16(AM, BH, ACC, 0, 0, 0);      \
    ACC = __builtin_amdgcn_mfma_f32_16x16x32_bf16(AH, BM, ACC, 0, 0, 0);      \
    ACC = __builtin_amdgcn_mfma_f32_16x16x32_bf16(AH, BH, ACC, 0, 0, 0);

// XOR-swizzled LDS address: rows x 128 cols of ushort,
// addr = row*128 + ((chunk ^ (row&15))<<3) + (col&7), chunk = col>>3.
__device__ __forceinline__ int swz(int row, int col) {
    return row * 128 + ((((col >> 3) ^ (row & 15))) << 3) + (col & 7);
}

// ---------------- fused MLP (+ prev step's update; + pools p1/p2 + hist) ---
// R6 geometry kept (M=64, grid 256, 8 waves, 1 block/CU). R7 adds:
// (a) explicit 1-deep W prefetch in GEMM1/GEMM2 (VGPR=88 showed compiler
//     didn't pipeline; MfmaUtil 22.7%); GEMM2's next-quarter W triple loads
//     before the h-phase VALU so L2 latency drains under it.
// (b) pools_kernel folded in: p1/p2 are block-local (4 l-rows x 128 cols);
//     recomputed from a 2KB ent LDS stage with the byte-identical summation
//     order; scale-0 hist built in LDS aliased onto dead hA, merged to ghist.
template <int UPD>
__global__ __launch_bounds__(512, 2) void mlp_kernel(
    float* __restrict__ z, const float* __restrict__ zr,
    const float* __restrict__ y, const float* __restrict__ mk,
    const unsigned short* __restrict__ W1h, const unsigned short* __restrict__ W1m,
    const unsigned short* __restrict__ W1l, const unsigned short* __restrict__ W2h,
    const unsigned short* __restrict__ W2m, const unsigned short* __restrict__ W2l,
    const float* __restrict__ b1, const float* __restrict__ tw,
    const float* __restrict__ b2, float t_feat,
    float* __restrict__ eps_buf, float* __restrict__ ent,
    const float* __restrict__ cA, const float* __restrict__ cB,
    const float* __restrict__ cG, float* __restrict__ accum,
    float* __restrict__ p1, float* __restrict__ p2,
    unsigned* __restrict__ ghist) {
    __shared__ unsigned short zA[3][8192];  // swizzled [row<64][col<128]
    __shared__ unsigned short hA[3][8192];  // swizzled h quarter, M=64
    __shared__ float entbuf[4][128];        // block's ent rows (pools fold)
    __shared__ float red1[8], red2[8];
    const int tid = threadIdx.x;
    const int w = tid >> 6, lane = tid & 63;  // w = 0..7
    const int quad = lane >> 4, m16 = lane & 15;
    const int l0 = blockIdx.x * 4;

    // ---- phase 1: (coeff-map update) + stats + stage split z into LDS ----
    float s1 = 0.f, s2 = 0.f;
#pragma unroll
    for (int e = 0; e < 4; ++e) {
        const int f = (e * 512 + tid) * 4;  // 0..8188, coalesced per e
        const int r_ = f >> 7, cb = f & 127;
        const int b = r_ & 15, il = r_ >> 4, l = l0 + il;
        const size_t g = ((size_t)b * 1024 + l) * 128 + cb;
        float4 zv = *(const float4*)(zr + g);
        const float4 yv = *(const float4*)(y + g);
        const float4 mv = *(const float4*)(mk + g);
        if (UPD) {
            const float4 ev = *(const float4*)(eps_buf + g);
            const int pix = l * 128 + cb;
            const float4 a4 = *(const float4*)(cA + pix);
            const float4 b4 = *(const float4*)(cB + pix);
            const float4 g4 = *(const float4*)(cG + pix);
            zv.x = a4.x * zv.x - b4.x * ev.x - g4.x * ((zv.x - yv.x) * mv.x);
            zv.y = a4.y * zv.y - b4.y * ev.y - g4.y * ((zv.y - yv.y) * mv.y);
            zv.z = a4.z * zv.z - b4.z * ev.z - g4.z * ((zv.z - yv.z) * mv.z);
            zv.w = a4.w * zv.w - b4.w * ev.w - g4.w * ((zv.w - yv.w) * mv.w);
            *(float4*)(z + g) = zv;
        }
        float oe;
        oe = (zv.x - yv.x) * mv.x; s1 += oe; s2 += oe * oe;
        oe = (zv.y - yv.y) * mv.y; s1 += oe; s2 += oe * oe;
        oe = (zv.z - yv.z) * mv.z; s1 += oe; s2 += oe * oe;
        oe = (zv.w - yv.w) * mv.w; s1 += oe; s2 += oe * oe;

        // swizzled staging (ushort4 = 8B per array; conflict-free)
        const int base = swz(r_, cb);
        const float xs[4] = {zv.x, zv.y, zv.z, zv.w};
        ushort4 vh, vm, vl;
        unsigned uh, um, ul;
        split3(xs[0], uh, um, ul); vh.x = uh >> 16; vm.x = um >> 16; vl.x = ul >> 16;
        split3(xs[1], uh, um, ul); vh.y = uh >> 16; vm.y = um >> 16; vl.y = ul >> 16;
        split3(xs[2], uh, um, ul); vh.z = uh >> 16; vm.z = um >> 16; vl.z = ul >> 16;
        split3(xs[3], uh, um, ul); vh.w = uh >> 16; vm.w = um >> 16; vl.w = ul >> 16;
        *(ushort4*)(&zA[0][base]) = vh;
        *(ushort4*)(&zA[1][base]) = vm;
        *(ushort4*)(&zA[2][base]) = vl;
    }
#pragma unroll
    for (int off = 32; off; off >>= 1) {
        s1 += __shfl_down(s1, off);
        s2 += __shfl_down(s2, off);
    }
    if (lane == 0) { red1[w] = s1; red2[w] = s2; }
    __syncthreads();  // staging + red complete
    if (tid == 0) {
        float a1 = 0.f, a2 = 0.f;
#pragma unroll
        for (int i = 0; i < 8; ++i) { a1 += red1[i]; a2 += red2[i]; }
        atomicAdd(&accum[0], a1);
        atomicAdd(&accum[1], a2);
    }

    // ---- GEMM1 (all H): acc1[q*4+il]; explicit 1-deep W prefetch ----
    floatx4 acc1[16];
#pragma unroll
    for (int i = 0; i < 16; ++i) acc1[i] = (floatx4){0.f, 0.f, 0.f, 0.f};

    {
        short8 Ah[4], Am[4], Al[4];
        short8 bh, bm, bl;
        {
            const size_t off0 = ((size_t)w * 64 + lane) * 8;  // kt=0,q=0
            bh = *(const short8*)(W1h + off0);
            bm = *(const short8*)(W1m + off0);
            bl = *(const short8*)(W1l + off0);
        }
#pragma unroll
        for (int it = 0; it < 16; ++it) {
            const int kt = it >> 2, q = it & 3;
            if (q == 0) {
#pragma unroll
                for (int il = 0; il < 4; ++il) {
                    const int fb = swz(il * 16 + m16, kt * 32 + quad * 8);
                    Ah[il] = *(const short8*)(&zA[0][fb]);
                    Am[il] = *(const short8*)(&zA[1][fb]);
                    Al[il] = *(const short8*)(&zA[2][fb]);
                }
            }
            short8 nbh = bh, nbm = bm, nbl = bl;
            if (it < 15) {
                const int itn = it + 1;
                const size_t off =
                    ((size_t)((itn >> 2) * 32 + (itn & 3) * 8 + w) * 64 + lane) * 8;
                nbh = *(const short8*)(W1h + off);
                nbm = *(const short8*)(W1m + off);
                nbl = *(const short8*)(W1l + off);
            }
#pragma unroll
            for (int il = 0; il < 4; ++il) {
                floatx4 a = acc1[q * 4 + il];
                MFMA6(Ah[il], Am[il], Al[il], bh, bm, bl, a);
                acc1[q * 4 + il] = a;
            }
            bh = nbh; bm = nbm; bl = nbl;
        }
    }

    // ---- quarter phases: gelu+split h -> hA, GEMM2; W2 prefetch spans
    //      the h-phase (next quarter's first triple loads at ktl==3) ----
    floatx4 acc2[4];
#pragma unroll
    for (int i = 0; i < 4; ++i) acc2[i] = (floatx4){0.f, 0.f, 0.f, 0.f};

    short8 ch, cm, cl;
    {
        const size_t off0 = ((size_t)w * 64 + lane) * 8;  // q=0,ktl=0
        ch = *(const short8*)(W2h + off0);
        cm = *(const short8*)(W2m + off0);
        cl = *(const short8*)(W2l + off0);
    }
#pragma unroll
    for (int q = 0; q < 4; ++q) {
        {
            const int colg = q * 128 + w * 16 + m16;
            const float bb = b1[colg] + t_feat * tw[colg];
            const int kcol = w * 16 + m16;  // quarter-local k col
#pragma unroll
            for (int il = 0; il < 4; ++il) {
#pragma unroll
                for (int r = 0; r < 4; ++r) {
                    const float x = gelu_fast(acc1[q * 4 + il][r] + bb);
                    unsigned uh, um, ul;
                    split3(x, uh, um, ul);
                    const int idx = swz(il * 16 + quad * 4 + r, kcol);
                    hA[0][idx] = (unsigned short)(uh >> 16);
                    hA[1][idx] = (unsigned short)(um >> 16);
                    hA[2][idx] = (unsigned short)(ul >> 16);
                }
            }
        }
        __syncthreads();  // hA writes visible

#pragma unroll
        for (int ktl = 0; ktl < 4; ++ktl) {
            const int jt = q * 4 + ktl;
            short8 nch = ch, ncm = cm, ncl = cl;
            if (jt < 15) {
                const size_t off = ((size_t)((jt + 1) * 8 + w) * 64 + lane) * 8;
                nch = *(const short8*)(W2h + off);
                ncm = *(const short8*)(W2m + off);
                ncl = *(const short8*)(W2l + off);
            }
            short8 Ah2[4], Am2[4], Al2[4];
#pragma unroll
            for (int il = 0; il < 4; ++il) {
                const int fb = swz(il * 16 + m16, ktl * 32 + quad * 8);
                Ah2[il] = *(const short8*)(&hA[0][fb]);
                Am2[il] = *(const short8*)(&hA[1][fb]);
                Al2[il] = *(const short8*)(&hA[2][fb]);
            }
#pragma unroll
            for (int il = 0; il < 4; ++il) {
                floatx4 a = acc2[il];
                MFMA6(Ah2[il], Am2[il], Al2[il], ch, cm, cl, a);
                acc2[il] = a;
            }
            ch = nch; cm = ncm; cl = ncl;
        }
        __syncthreads();  // all hA reads done before next quarter's write
    }

    // ---- epilogue: +b2, write eps, ent = mean_b |eps|; stage ent in LDS ---
    {
        const int col = w * 16 + m16;
        const float bb2 = b2[col];
#pragma unroll
        for (int il = 0; il < 4; ++il) {
            float pa = 0.f;
#pragma unroll
            for (int r = 0; r < 4; ++r) {
                const float e = acc2[il][r] + bb2;
                const int b = quad * 4 + r;
                eps_buf[((size_t)b * 1024 + l0 + il) * 128 + col] = e;
                pa += fabsf(e);
            }
            pa += __shfl_xor(pa, 16);
            pa += __shfl_xor(pa, 32);
            if (quad == 0) {
                const float ev = pa * (1.0f / 16.0f);
                ent[(l0 + il) * 128 + col] = ev;
                entbuf[il][col] = ev;
            }
        }
    }

    // ---- pools fold: hist (packed LDS, aliased onto dead hA) + p1 + p2 ----
    unsigned* lhist = (unsigned*)&hA[0][0];  // 8192 u32 = 32KB (hA is dead)
    for (int i = tid; i < 8192; i += 512) lhist[i] = 0u;
    __syncthreads();  // entbuf + lhist-zero visible
    if (tid < 512) {
        const float v = entbuf[tid >> 7][tid & 127];
        const unsigned b = fordbits(__float_as_uint(v)) >> 18;
        atomicAdd(&lhist[b >> 1], 1u << ((b & 1) << 4));
    }
    if (tid < 128) {  // p1: rows 2*bid+ir, 64 cols; proven order r0c0,r0c1,r1c0,r1c1
        const int ir = tid >> 6, c = tid & 63;
        float s = entbuf[2 * ir][2 * c];
        s += entbuf[2 * ir][2 * c + 1];
        s += entbuf[2 * ir + 1][2 * c];
        s += entbuf[2 * ir + 1][2 * c + 1];
        p1[(2 * (int)blockIdx.x + ir) * 64 + c] = s * 0.25f;
    }
    if (tid < 32) {  // p2: row bid, 32 cols; proven order ii outer, jj inner
        const int c = tid;
        float s = 0.f;
#pragma unroll
        for (int ii = 0; ii < 4; ++ii) {
            s += entbuf[ii][4 * c];
            s += entbuf[ii][4 * c + 1];
            s += entbuf[ii][4 * c + 2];
            s += entbuf[ii][4 * c + 3];
        }
        p2[(int)blockIdx.x * 32 + c] = s * 0.0625f;
    }
    __syncthreads();  // lhist complete
    for (int i = tid; i < 8192; i += 512) {
        const unsigned v = lhist[i];
        if (v & 0xFFFFu) atomicAdd(&ghist[2 * i], v & 0xFFFFu);
        if (v >> 16) atomicAdd(&ghist[2 * i + 1], v >> 16);
    }
}

// ======================= select path, barrier-free =========================
// Kernel boundaries are the global barriers; all cross-kernel reads are
// plain loads. pools_kernel is gone: p1/p2/hist from mlp, p3 in thresh.

#define CAND_CAP 16384

// ---- register-resident exact Kth-largest on pre-loaded values ----
template <int NPT4, int N, unsigned K>
__device__ __forceinline__ void small_select_vals(
    const float4* xv, unsigned* __restrict__ gout, const int t,
    const int w8, unsigned* __restrict__ histcand,
    unsigned* __restrict__ part, unsigned (*hrep)[512],
    unsigned* sh_b, unsigned* sh_krem, unsigned* sh_cnt, unsigned* sh_d,
    unsigned* sh_k2) {
    unsigned u[NPT4 * 4];
#pragma unroll
    for (int i = 0; i < NPT4; ++i) {
        u[4 * i + 0] = fordbits(__float_as_uint(xv[i].x));
        u[4 * i + 1] = fordbits(__float_as_uint(xv[i].y));
        u[4 * i + 2] = fordbits(__float_as_uint(xv[i].z));
        u[4 * i + 3] = fordbits(__float_as_uint(xv[i].w));
    }
    if (t == 0) { *sh_b = 0u; *sh_krem = 1u; *sh_cnt = 0u; *sh_d = 0u; *sh_k2 = 1u; }
    for (int i = t; i < 16384; i += 1024) histcand[i] = 0u;
    __syncthreads();
#pragma unroll
    for (int j = 0; j < NPT4 * 4; ++j) atomicAdd(&histcand[u[j] >> 18], 1u);
    __syncthreads();
    // suffix scan over 16384 bins: 16/thread, then 1024-block scan
    {
        unsigned s = 0;
#pragma unroll
        for (int j = 0; j < 16; ++j) s += histcand[t * 16 + j];
        part[t] = s;
    }
    __syncthreads();
    for (int off = 1; off < 1024; off <<= 1) {
        const unsigned v = (t + off < 1024) ? part[t + off] : 0u;
        __syncthreads();
        part[t] += v;
        __syncthreads();
    }
    {
        const unsigned suf = part[t];
        const unsigned sufn = (t < 1023) ? part[t + 1] : 0u;
        if (suf >= K && sufn < K) {
            unsigned run = sufn;
            for (int b = 15; b >= 0; --b) {
                const unsigned hb = histcand[t * 16 + b];
                run += hb;
                if (run >= K) {
                    *sh_b = (unsigned)(t * 16 + b);
                    *sh_krem = K - (run - hb);
                    break;
                }
            }
        }
    }
    __syncthreads();
    const unsigned b14 = *sh_b;
    unsigned krem = *sh_krem;
    __syncthreads();  // all histcand reads done before cand overwrite
    // compact candidates from registers into histcand-as-cand
#pragma unroll
    for (int j = 0; j < NPT4 * 4; ++j)
        if ((u[j] >> 18) == b14) {
            const unsigned p = atomicAdd(sh_cnt, 1u);
            if (p < CAND_CAP) histcand[p] = u[j];
        }
    __syncthreads();
    const unsigned cnt = *sh_cnt;
    const bool inlds = (cnt <= CAND_CAP);
    // ---- refine bits 17..9 ----
    for (int i = t; i < 4096; i += 1024) ((unsigned*)hrep)[i] = 0u;
    __syncthreads();
    if (inlds) {
        for (unsigned i = t; i < cnt; i += 1024)
            atomicAdd(&hrep[w8][(histcand[i] >> 9) & 511u], 1u);
    } else {
#pragma unroll
        for (int j = 0; j < NPT4 * 4; ++j)
            if ((u[j] >> 18) == b14)
                atomicAdd(&hrep[w8][(u[j] >> 9) & 511u], 1u);
    }
    __syncthreads();
    if (t < 512) {
        unsigned s = 0;
#pragma unroll
        for (int r = 0; r < 8; ++r) s += hrep[r][t];
        part[t] = s;
    }
    __syncthreads();
    for (int off = 1; off < 512; off <<= 1) {
        unsigned v = 0u;
        if (t < 512) v = (t + off < 512) ? part[t + off] : 0u;
        __syncthreads();
        if (t < 512) part[t] += v;
        __syncthreads();
    }
    if (t < 512) {
        const unsigned suf = part[t];
        const unsigned sufn = (t < 511) ? part[t + 1] : 0u;
        if (suf >= krem && sufn < krem) { *sh_d = (unsigned)t; *sh_k2 = krem - sufn; }
    }
    __syncthreads();
    const unsigned dA = *sh_d;
    krem = *sh_k2;
    __syncthreads();
    // ---- refine bits 8..0 ----
    for (int i = t; i < 4096; i += 1024) ((unsigned*)hrep)[i] = 0u;
    __syncthreads();
    if (inlds) {
        for (unsigned i = t; i < cnt; i += 1024) {
            const unsigned c = histcand[i];
            if (((c >> 9) & 511u) == dA) atomicAdd(&hrep[w8][c & 511u], 1u);
        }
    } else {
#pragma unroll
        for (int j = 0; j < NPT4 * 4; ++j)
            if ((u[j] >> 18) == b14 && ((u[j] >> 9) & 511u) == dA)
                atomicAdd(&hrep[w8][u[j] & 511u], 1u);
    }
    __syncthreads();
    if (t < 512) {
        unsigned s = 0;
#pragma unroll
        for (int r = 0; r < 8; ++r) s += hrep[r][t];
        part[t] = s;
    }
    __syncthreads();
    for (int off = 1; off < 512; off <<= 1) {
        unsigned v = 0u;
        if (t < 512) v = (t + off < 512) ? part[t + off] : 0u;
        __syncthreads();
        if (t < 512) part[t] += v;
        __syncthreads();
    }
    if (t < 512) {
        const unsigned suf = part[t];
        const unsigned sufn = (t < 511) ? part[t + 1] : 0u;
        if (suf >= krem && sufn < krem)
            gout[0] = (b14 << 18) | (dA << 9) | (unsigned)t;
    }
}

// ---- S2: exact K-th-largest thresholds. 4 blocks x 1024 thr (1/scale). ----
// Scale 3 additionally computes p3 from ent (proven summation order) and
// writes it for coeff; values stay in registers for its own select (avoids
// same-kernel global RAW through L1).
__global__ __launch_bounds__(1024, 1) void thresh_kernel(
    const float* __restrict__ ent, const float* __restrict__ p1,
    const float* __restrict__ p2, float* __restrict__ p3,
    const unsigned* __restrict__ ghist, unsigned* __restrict__ gprefix) {
    const int scale = blockIdx.x, t = threadIdx.x;
    __shared__ unsigned histcand[16384];  // 14-bit hist, then candidates
    __shared__ unsigned part[1024];
    __shared__ unsigned hrep[8][512];
    __shared__ unsigned sh_b, sh_krem, sh_cnt, sh_d, sh_k2;
    const int w8 = (t >> 6) & 7;

    if (scale == 1) {
        float4 xv[8];
#pragma unroll
        for (int i = 0; i < 8; ++i) xv[i] = ((const float4*)p1)[t + i * 1024];
        small_select_vals<8, 32768, 6553u>(xv, &gprefix[1], t, w8, histcand,
                                           part, hrep, &sh_b, &sh_krem,
                                           &sh_cnt, &sh_d, &sh_k2);
        return;
    }
    if (scale == 2) {
        float4 xv[2];
#pragma unroll
        for (int i = 0; i < 2; ++i) xv[i] = ((const float4*)p2)[t + i * 1024];
        small_select_vals<2, 8192, 1638u>(xv, &gprefix[2], t, w8, histcand,
                                          part, hrep, &sh_b, &sh_krem,
                                          &sh_cnt, &sh_d, &sh_k2);
        return;
    }
    if (scale == 3) {
        // compute p3 (w=8 pools) from ent, proven order; 4 entries/thread
        float4 xv[1];
        if (t < 512) {
            float sv[4];
#pragma unroll
            for (int jdx = 0; jdx < 4; ++jdx) {
                const int e = t * 4 + jdx;  // < 2048
                const int r = e >> 4, c = e & 15;
                float s = 0.f;
#pragma unroll
                for (int ii = 0; ii < 8; ++ii) {
                    const float4 ea =
                        *(const float4*)(ent + (((r * 8 + ii) << 7) + c * 8));
                    const float4 eb =
                        *(const float4*)(ent + (((r * 8 + ii) << 7) + c * 8 + 4));
                    s += ea.x; s += ea.y; s += ea.z; s += ea.w;
                    s += eb.x; s += eb.y; s += eb.z; s += eb.w;
                }
                sv[jdx] = s * (1.0f / 64.0f);
            }
            xv[0] = (float4){sv[0], sv[1], sv[2], sv[3]};
            *(float4*)(p3 + t * 4) = xv[0];  // for coeff (next dispatch)
        } else {
            xv[0] = (float4){-1e30f, -1e30f, -1e30f, -1e30f};
        }
        small_select_vals<1, 2048, 409u>(xv, &gprefix[3], t, w8, histcand,
                                         part, hrep, &sh_b, &sh_krem,
                                         &sh_cnt, &sh_d, &sh_k2);
        return;
    }

    // ---------------- scale 0: ent, N=131072, K=26214 ----------------
    const unsigned K = 26214u;
    if (t == 0) { sh_b = 0u; sh_krem = 1u; sh_cnt = 0u; sh_d = 0u; sh_k2 = 1u; }

    // 14-bit bucket from global hist: 16 bins/thread + block suffix scan
    {
        unsigned s = 0;
        const uint4* h4 = (const uint4*)(ghist + t * 16);
#pragma unroll
        for (int j = 0; j < 4; ++j) {
            const uint4 x = h4[j];
            s += x.x + x.y + x.z + x.w;
        }
        part[t] = s;
    }
    __syncthreads();
    for (int off = 1; off < 1024; off <<= 1) {
        const unsigned v = (t + off < 1024) ? part[t + off] : 0u;
        __syncthreads();
        part[t] += v;
        __syncthreads();
    }
    {
        const unsigned suf = part[t];
        const unsigned sufn = (t < 1023) ? part[t + 1] : 0u;
        if (suf >= K && sufn < K) {  // unique crossing chunk
            unsigned run = sufn;
            for (int b = 15; b >= 0; --b) {
                const unsigned hb = ghist[t * 16 + b];
                run += hb;
                if (run >= K) {
                    sh_b = (unsigned)(t * 16 + b);
                    sh_krem = K - (run - hb);
                    break;
                }
            }
        }
    }
    __syncthreads();
    const unsigned b14 = sh_b;
    unsigned krem = sh_krem;

    // compact in-bucket candidates into LDS; batched 8x float4 loads
    for (int base = 0; base < 32768; base += 8192) {
        float4 w4[8];
#pragma unroll
        for (int i = 0; i < 8; ++i)
            w4[i] = ((const float4*)ent)[base + i * 1024 + t];
#pragma unroll
        for (int i = 0; i < 8; ++i) {
            const float xs[4] = {w4[i].x, w4[i].y, w4[i].z, w4[i].w};
#pragma unroll
            for (int j = 0; j < 4; ++j) {
                const unsigned uu = fordbits(__float_as_uint(xs[j]));
                if ((uu >> 18) == b14) {
                    const unsigned p = atomicAdd(&sh_cnt, 1u);
                    if (p < CAND_CAP) histcand[p] = uu;
                }
            }
        }
    }
    __syncthreads();
    const unsigned cnt = sh_cnt;
    const bool inlds = (cnt <= CAND_CAP);

    // ---- refine bits 17..9 ----
    for (int i = t; i < 4096; i += 1024) ((unsigned*)hrep)[i] = 0u;
    __syncthreads();
    if (inlds) {
        for (unsigned i = t; i < cnt; i += 1024)
            atomicAdd(&hrep[w8][(histcand[i] >> 9) & 511u], 1u);
    } else {
        for (int base = 0; base < 32768; base += 8192) {
            float4 w4[8];
#pragma unroll
            for (int i = 0; i < 8; ++i)
                w4[i] = ((const float4*)ent)[base + i * 1024 + t];
#pragma unroll
            for (int i = 0; i < 8; ++i) {
                const float xs[4] = {w4[i].x, w4[i].y, w4[i].z, w4[i].w};
#pragma unroll
                for (int j = 0; j < 4; ++j) {
                    const unsigned uu = fordbits(__float_as_uint(xs[j]));
                    if ((uu >> 18) == b14)
                        atomicAdd(&hrep[w8][(uu >> 9) & 511u], 1u);
                }
            }
        }
    }
    __syncthreads();
    if (t < 512) {
        unsigned s = 0;
#pragma unroll
        for (int r = 0; r < 8; ++r) s += hrep[r][t];
        part[t] = s;
    }
    __syncthreads();
    for (int off = 1; off < 512; off <<= 1) {
        unsigned v = 0u;
        if (t < 512) v = (t + off < 512) ? part[t + off] : 0u;
        __syncthreads();
        if (t < 512) part[t] += v;
        __syncthreads();
    }
    if (t < 512) {
        const unsigned suf = part[t];
        const unsigned sufn = (t < 511) ? part[t + 1] : 0u;
        if (suf >= krem && sufn < krem) { sh_d = (unsigned)t; sh_k2 = krem - sufn; }
    }
    __syncthreads();
    const unsigned dA = sh_d;
    krem = sh_k2;
    __syncthreads();

    // ---- refine bits 8..0 ----
    for (int i = t; i < 4096; i += 1024) ((unsigned*)hrep)[i] = 0u;
    __syncthreads();
    if (inlds) {
        for (unsigned i = t; i < cnt; i += 1024) {
            const unsigned c = histcand[i];
            if (((c >> 9) & 511u) == dA) atomicAdd(&hrep[w8][c & 511u], 1u);
        }
    } else {
        for (int base = 0; base < 32768; base += 8192) {
            float4 w4[8];
#pragma unroll
            for (int i = 0; i < 8; ++i)
                w4[i] = ((const float4*)ent)[base + i * 1024 + t];
#pragma unroll
            for (int i = 0; i < 8; ++i) {
                const float xs[4] = {w4[i].x, w4[i].y, w4[i].z, w4[i].w};
#pragma unroll
                for (int j = 0; j < 4; ++j) {
                    const unsigned uu = fordbits(__float_as_uint(xs[j]));
                    if ((uu >> 18) == b14 && ((uu >> 9) & 511u) == dA)
                        atomicAdd(&hrep[w8][uu & 511u], 1u);
                }
            }
        }
    }
    __syncthreads();
    if (t < 512) {
        unsigned s = 0;
#pragma unroll
        for (int r = 0; r < 8; ++r) s += hrep[r][t];
        part[t] = s;
    }
    __syncthreads();
    for (int off = 1; off < 512; off <<= 1) {
        unsigned v = 0u;
        if (t < 512) v = (t + off < 512) ? part[t + off] : 0u;
        __syncthreads();
        if (t < 512) part[t] += v;
        __syncthreads();
    }
    if (t < 512) {
        const unsigned suf = part[t];
        const unsigned sufn = (t < 511) ? part[t + 1] : 0u;
        if (suf >= krem && sufn < krem)
            gprefix[0] = (b14 << 18) | (dA << 9) | (unsigned)t;
    }
}

// ---- S3: per-pixel coeff maps, plain streaming loads; zeroes hist next ----
__global__ __launch_bounds__(256) void coeff_kernel(
    const float* __restrict__ ent, const float* __restrict__ p1,
    const float* __restrict__ p2, const float* __restrict__ p3,
    const unsigned* __restrict__ gprefix, const float* __restrict__ accum_si,
    float* __restrict__ cA, float* __restrict__ cB, float* __restrict__ cG,
    unsigned* __restrict__ ghist, float base_a, float base_b, float h_lam) {
    const int i = blockIdx.x * 256 + threadIdx.x;  // < 131072
    // zero 14-bit histogram for the next step's mlp hist
    if (i < 16384) ghist[i] = 0u;

    const unsigned t0 = gprefix[0], t1 = gprefix[1], t2 = gprefix[2],
                   t3 = gprefix[3];
    const float mean = accum_si[0] * (1.0f / (float)BLC);
    const float var = accum_si[1] * (1.0f / (float)BLC) - mean * mean;
    const float vinv = 1.0f / (var + 1e-8f);

    const int l = i >> 7, c = i & 127;
    float ent_v = 0.f;
    bool sel = false;
    const float v0 = ent[i];
    if (fordbits(__float_as_uint(v0)) >= t0) { ent_v = v0; sel = true; }
    else {
        const float v1 = p1[((l >> 1) << 6) + (c >> 1)];
        if (fordbits(__float_as_uint(v1)) >= t1) { ent_v = v1; sel = true; }
        else {
            const float v2 = p2[((l >> 2) << 5) + (c >> 2)];
            if (fordbits(__float_as_uint(v2)) >= t2) { ent_v = v2; sel = true; }
            else {
                const float v3 = p3[((l >> 3) << 4) + (c >> 3)];
                if (fordbits(__float_as_uint(v3)) >= t3) { ent_v = v3; sel = true; }
            }
        }
    }
    if (sel) {
        float corr;
        if (ent_v > 0.5f)
            corr = 1.0f + h_lam + h_lam * h_lam * (1.0f / 3.0f);
        else if (ent_v > 0.1f)
            corr = 1.0f + 0.5f * h_lam;
        else
            corr = 1.0f;
        cA[i] = base_a;
        cB[i] = base_b * corr;
        cG[i] = (2.0f * ent_v / (ent_v + 1.0f)) * vinv;
    } else {
        cA[i] = 1.0f;
        cB[i] = 0.f;
        cG[i] = 0.f;
    }
}

// ---------------- standalone final update (coeff-map streaming) ------------
__global__ __launch_bounds__(256) void update_kernel(
    float* __restrict__ z, const float* __restrict__ y,
    const float* __restrict__ mk, const float* __restrict__ eps,
    const float* __restrict__ cA, const float* __restrict__ cB,
    const float* __restrict__ cG) {
    const int idx = blockIdx.x * 256 + threadIdx.x;  // < BLC
    const int p = idx & (LC - 1);
    const float zi = z[idx];
    z[idx] = cA[p] * zi - cB[p] * eps[idx] - cG[p] * ((zi - y[idx]) * mk[idx]);
}

// ---------------------------------------------------------------------------
extern "C" void kernel_launch(void* const* d_in, const int* in_sizes, int n_in,
                              void* d_out, int out_size, void* d_ws,
                              size_t ws_size, hipStream_t stream) {
    const float* y_obs = (const float*)d_in[0];
    const float* mask = (const float*)d_in[1];
    const float* z_init = (const float*)d_in[2];
    const float* W1 = (const float*)d_in[3];
    const float* b1 = (const float*)d_in[4];
    const float* W2 = (const float*)d_in[5];
    const float* b2 = (const float*)d_in[6];
    const float* tw = (const float*)d_in[7];
    float* z = (float*)d_out;
    float* ws = (float*)d_ws;

    // workspace layout (float offsets); end = 2877452 floats = 11,509,808 B
    float* eps = ws;                                 // 2097152
    float* ent = ws + 2097152;                       // 131072
    float* p1 = ws + 2228224;                        // 32768
    float* p2 = ws + 2260992;                        // 8192
    float* p3 = ws + 2269184;                        // 2048
    float* cA = ws + 2271232;                        // 131072
    float* cB = ws + 2402304;                        // 131072
    float* cG = ws + 2533376;                        // 131072
    // zero block: accum[8] | gprefix[4] | ghist[16384] (contig 16396 u32)
    float* accum = ws + 2664448;                     // 8 (2 per step)
    unsigned* gprefix = (unsigned*)(ws + 2664456);   // 4
    unsigned* ghist = (unsigned*)(ws + 2664460);     // 16384 u32
    unsigned short* W1h = (unsigned short*)(ws + 2680844);  // 65536 u16 each
    unsigned short* W1m = (unsigned short*)(ws + 2713612);
    unsigned short* W1l = (unsigned short*)(ws + 2746380);
    unsigned short* W2h = (unsigned short*)(ws + 2779148);
    unsigned short* W2m = (unsigned short*)(ws + 2811916);
    unsigned short* W2l = (unsigned short*)(ws + 2844684);

    // diffusion schedule in fp32 (input-independent)
    float alpha_[1000], sigma_[1000], lam_[1000];
    {
        float ac = 1.0f;
        for (int i = 0; i < 1000; ++i) {
            const float beta = 1e-4f + (0.02f - 1e-4f) * ((float)i / 999.0f);
            ac = ac * (1.0f - beta);
            alpha_[i] = sqrtf(ac);
            sigma_[i] = sqrtf(1.0f - ac);
            lam_[i] = logf(alpha_[i]) - logf(sigma_[i]);
        }
    }
    float tf[4], hl[4], ba[4], bb[4];
    for (int si = 0; si < 4; ++si) {
        const int k = 999 - si * 250;
        const int kp = (k - 250 > 0) ? (k - 250) : 0;
        tf[si] = (float)k / 1000.0f;
        hl[si] = lam_[kp] - lam_[k];
        ba[si] = alpha_[kp] / alpha_[k];
        bb[si] = sigma_[kp] * (expf(hl[si]) - 1.0f);
    }

    // wsplit also zeroes accum|gprefix|ghist every launch/replay
    wsplit_kernel<<<512, 256, 0, stream>>>(W1, W2, W1h, W1m, W1l, W2h, W2m,
                                           W2l, (unsigned*)accum);

    for (int si = 0; si < 4; ++si) {
        // z is first WRITTEN at si=1; si=0,1 read z_init directly (no memcpy)
        const float* zrd = (si <= 1) ? z_init : z;
        if (si == 0) {
            mlp_kernel<0><<<256, 512, 0, stream>>>(
                z, zrd, y_obs, mask, W1h, W1m, W1l, W2h, W2m, W2l, b1, tw, b2,
                tf[0], eps, ent, cA, cB, cG, accum, p1, p2, ghist);
        } else {
            mlp_kernel<1><<<256, 512, 0, stream>>>(
                z, zrd, y_obs, mask, W1h, W1m, W1l, W2h, W2m, W2l, b1, tw, b2,
                tf[si], eps, ent, cA, cB, cG, accum + 2 * si, p1, p2, ghist);
        }
        thresh_kernel<<<4, 1024, 0, stream>>>(ent, p1, p2, p3, ghist, gprefix);
        coeff_kernel<<<512, 256, 0, stream>>>(ent, p1, p2, p3, gprefix,
                                              accum + 2 * si, cA, cB, cG,
                                              ghist, ba[si], bb[si], hl[si]);
    }
    update_kernel<<<8192, 256, 0, stream>>>(z, y_obs, mask, eps, cA, cB, cG);
}